// Round 2
// baseline (380.444 us; speedup 1.0000x reference)
//
#include <hip/hip_runtime.h>
#include <math.h>

#define NG 300
#define NP 100000
#define NC 80
#define PRED_COLS 85   // 5 + NC
#define ALPHA_C 0.75f
#define BETA_C  1.0f
#define EPS_C   1e-7f
#define TPB 256
#define BCH 8                 // top-k chunks per gt row
#define CHUNK (NP / BCH)      // 12500
#define KCAP 10

// ---------------------------------------------------------------------------
// Kernel A: cost matrix.  One thread per prediction; loop over all 300 gts.
// gt descriptors staged in LDS.  If USE_PROBS, the 80 class sigmoids per pred
// are computed once and round-tripped through a block-local [c][lane] slice of
// d_ws so the inner-loop prob read is a coalesced 256B/wave stream (instead of
// a 64-line/wave gather with stride 340B).
// ---------------------------------------------------------------------------
template <bool USE_PROBS>
__global__ __launch_bounds__(TPB) void cost_kernel(
    const float* __restrict__ preds, const float* __restrict__ gt_boxes,
    const int* __restrict__ gt_classes, float* __restrict__ cost,
    float* __restrict__ probs)
{
    __shared__ float sgx1[NG], sgy1[NG], sgx2[NG], sgy2[NG];
    __shared__ float sgar[NG], sgcx[NG], sgcy[NG], sgat[NG];
    __shared__ int   sgcl[NG];

    for (int i = threadIdx.x; i < NG; i += TPB) {
        float x1 = gt_boxes[i * 4 + 0], y1 = gt_boxes[i * 4 + 1];
        float x2 = gt_boxes[i * 4 + 2], y2 = gt_boxes[i * 4 + 3];
        sgx1[i] = x1; sgy1[i] = y1; sgx2[i] = x2; sgy2[i] = y2;
        sgar[i] = fmaxf(x2 - x1, 0.f) * fmaxf(y2 - y1, 0.f);
        sgcx[i] = (x1 + x2) * 0.5f;
        sgcy[i] = (y1 + y2) * 0.5f;
        sgat[i] = atanf(fmaxf(x2 - x1, EPS_C) / fmaxf(y2 - y1, EPS_C));
        sgcl[i] = gt_classes[i];
    }
    __syncthreads();

    int p = blockIdx.x * TPB + threadIdx.x;
    if (p >= NP) return;

    const float* row = preds + (size_t)p * PRED_COLS;
    float xc = row[0], yc = row[1], w = row[2], h = row[3];
    float px1 = xc - w * 0.5f, py1 = yc - h * 0.5f;
    float px2 = xc + w * 0.5f, py2 = yc + h * 0.5f;
    float areap = fmaxf(px2 - px1, 0.f) * fmaxf(py2 - py1, 0.f);
    float pcx = (px1 + px2) * 0.5f, pcy = (py1 + py2) * 0.5f;
    float atp = atanf(fmaxf(px2 - px1, EPS_C) / fmaxf(py2 - py1, EPS_C));

    float* pw = nullptr;
    if (USE_PROBS) {
        pw = probs + (size_t)blockIdx.x * TPB * NC + threadIdx.x;
        for (int c = 0; c < NC; ++c) {
            float l = row[5 + c];
            pw[(size_t)c * TPB] = 1.f / (1.f + expf(-l));
        }
    }

    const float VC = (float)(4.0 / (M_PI * M_PI));
    size_t outIdx = (size_t)p;
    for (int g = 0; g < NG; ++g) {
        float gx1 = sgx1[g], gy1 = sgy1[g], gx2 = sgx2[g], gy2 = sgy2[g];
        float xx1 = fmaxf(px1, gx1), yy1 = fmaxf(py1, gy1);
        float xx2 = fminf(px2, gx2), yy2 = fminf(py2, gy2);
        float inter = fmaxf(xx2 - xx1, 0.f) * fmaxf(yy2 - yy1, 0.f);
        float uni = areap + sgar[g] - inter + EPS_C;
        float iou = inter / uni;
        float dx = pcx - sgcx[g], dy = pcy - sgcy[g];
        float cd2 = dx * dx + dy * dy;
        float cw = fmaxf(fmaxf(px2, gx2) - fminf(px1, gx1), EPS_C);
        float ch = fmaxf(fmaxf(py2, gy2) - fminf(py1, gy1), EPS_C);
        float c2 = cw * cw + ch * ch + EPS_C;
        float dat = sgat[g] - atp;
        float v = VC * dat * dat;
        float alpha_t = v / (1.f - iou + v + EPS_C);
        float ciou = iou - cd2 / c2 - alpha_t * v;

        float prob;
        if (USE_PROBS) {
            prob = pw[(size_t)sgcl[g] * TPB];
        } else {
            prob = 1.f / (1.f + expf(-row[5 + sgcl[g]]));
        }
        float cst = ALPHA_C * (1.f - prob) +
                    BETA_C * (1.f - fminf(fmaxf(ciou, 0.f), 1.f));
        cost[outIdx] = cst;
        outIdx += NP;
    }
}

// ---------------------------------------------------------------------------
// Kernel B: partial top-10 per (gt, chunk).  float4 scan, register top-10 with
// fully-unrolled static-index insertion, LDS merge tree.  Comparator is
// (cost asc, idx asc) lexicographic == jax.lax.top_k tie-breaking.
// ---------------------------------------------------------------------------
__global__ __launch_bounds__(TPB) void topk_partial(
    const float* __restrict__ cost, float* __restrict__ lc, int* __restrict__ li)
{
    int g  = blockIdx.x / BCH;
    int ch = blockIdx.x % BCH;
    const float* base = cost + (size_t)g * NP + (size_t)ch * CHUNK;

    float c[KCAP]; int id[KCAP];
#pragma unroll
    for (int k = 0; k < KCAP; ++k) { c[k] = INFINITY; id[k] = 0x7fffffff; }

    const float4* b4 = (const float4*)base;
    const int NV = CHUNK / 4;  // 3125
    for (int i = threadIdx.x; i < NV; i += TPB) {
        float4 v = b4[i];
        int pbase = ch * CHUNK + i * 4;
        float vv[4] = {v.x, v.y, v.z, v.w};
#pragma unroll
        for (int q = 0; q < 4; ++q) {
            float val = vv[q];
            if (val < c[KCAP - 1]) {  // ties excluded: existing has smaller idx
#pragma unroll
                for (int j = KCAP - 1; j >= 0; --j) {
                    bool lt = (val < c[j]);
                    if (lt) {
                        bool ltm = (j > 0) && (val < c[j - 1]);
                        if (ltm) { c[j] = c[j - 1]; id[j] = id[j - 1]; }
                        else     { c[j] = val;      id[j] = pbase + q; }
                    }
                }
            }
        }
    }

    __shared__ float sc[TPB][KCAP];
    __shared__ int   si[TPB][KCAP];
    int t = threadIdx.x;
#pragma unroll
    for (int k = 0; k < KCAP; ++k) { sc[t][k] = c[k]; si[t][k] = id[k]; }
    __syncthreads();

    for (int stride = TPB / 2; stride >= 1; stride >>= 1) {
        if (t < stride) {
            int ia = 0, ib = 0;
            float rc[KCAP]; int ri[KCAP];
#pragma unroll
            for (int k = 0; k < KCAP; ++k) {
                float ca = sc[t][ia], cb = sc[t + stride][ib];
                int   ja = si[t][ia], jb = si[t + stride][ib];
                bool ta = (ca < cb) || (ca == cb && ja < jb);
                rc[k] = ta ? ca : cb; ri[k] = ta ? ja : jb;
                ia += ta ? 1 : 0; ib += ta ? 0 : 1;
            }
#pragma unroll
            for (int k = 0; k < KCAP; ++k) { sc[t][k] = rc[k]; si[t][k] = ri[k]; }
        }
        __syncthreads();
    }

    if (t == 0) {
        float* oc = lc + ((size_t)g * BCH + ch) * KCAP;
        int*   oi = li + ((size_t)g * BCH + ch) * KCAP;
#pragma unroll
        for (int k = 0; k < KCAP; ++k) { oc[k] = sc[0][k]; oi[k] = si[0][k]; }
    }
}

// ---------------------------------------------------------------------------
// Kernel C: merge the 8 partial lists per gt, compute Kt from the epoch
// schedule (banker's rounding, matching Python round()), write assignments.
// ---------------------------------------------------------------------------
__global__ __launch_bounds__(64) void topk_final(
    const float* __restrict__ lc, const int* __restrict__ li,
    const int* __restrict__ epoch, const int* __restrict__ total_epochs,
    float* __restrict__ out_assign)
{
    int g = blockIdx.x;
    __shared__ float sc[BCH * KCAP];
    __shared__ int   si[BCH * KCAP];
    for (int i = threadIdx.x; i < BCH * KCAP; i += 64) {
        sc[i] = lc[(size_t)g * BCH * KCAP + i];
        si[i] = li[(size_t)g * BCH * KCAP + i];
    }
    __syncthreads();

    if (threadIdx.x == 0) {
        int ep = epoch[0], te = total_epochs[0];
        int denom = te - 1; if (denom < 1) denom = 1;
        double tt = (double)ep / (double)denom;
        double val = 10.0 - 9.0 * tt;
        int K = (int)rint(val);
        if (K < 1) K = 1; if (K > 10) K = 10;
        int Kt = (K < NP) ? K : NP;

        for (int k = 0; k < Kt; ++k) {
            float bc = INFINITY; int bi = 0x7fffffff; int bpos = 0;
            for (int j = 0; j < BCH * KCAP; ++j) {
                float cc = sc[j]; int ii = si[j];
                if (cc < bc || (cc == bc && ii < bi)) { bc = cc; bi = ii; bpos = j; }
            }
            sc[bpos] = INFINITY; si[bpos] = 0x7fffffff;
            out_assign[2 * ((size_t)g * Kt + k) + 0] = (float)bi;
            out_assign[2 * ((size_t)g * Kt + k) + 1] = (float)g;
        }
    }
}

// ---------------------------------------------------------------------------
extern "C" void kernel_launch(void* const* d_in, const int* in_sizes, int n_in,
                              void* d_out, int out_size, void* d_ws, size_t ws_size,
                              hipStream_t stream)
{
    const float* preds        = (const float*)d_in[0];
    const float* gt_boxes     = (const float*)d_in[1];
    const int*   gt_classes   = (const int*)d_in[2];
    const int*   epoch        = (const int*)d_in[3];
    const int*   total_epochs = (const int*)d_in[4];

    float* cost       = (float*)d_out;
    float* out_assign = cost + (size_t)NG * NP;

    const int ablocks = (NP + TPB - 1) / TPB;  // 391
    size_t probBytes  = (size_t)ablocks * TPB * NC * sizeof(float);  // ~32 MB
    size_t nlist      = (size_t)NG * BCH * KCAP;                     // 24000

    char* wsp = (char*)d_ws;
    bool useProbs = ws_size >= probBytes + nlist * 8;
    float* probs; float* lc; int* li;
    if (useProbs) {
        probs = (float*)wsp;
        lc    = (float*)(wsp + probBytes);
        li    = (int*)  (wsp + probBytes + nlist * sizeof(float));
    } else {
        probs = nullptr;
        lc    = (float*)wsp;
        li    = (int*)  (wsp + nlist * sizeof(float));
    }

    if (useProbs)
        cost_kernel<true ><<<ablocks, TPB, 0, stream>>>(preds, gt_boxes, gt_classes, cost, probs);
    else
        cost_kernel<false><<<ablocks, TPB, 0, stream>>>(preds, gt_boxes, gt_classes, cost, probs);

    topk_partial<<<NG * BCH, TPB, 0, stream>>>(cost, lc, li);
    topk_final<<<NG, 64, 0, stream>>>(lc, li, epoch, total_epochs, out_assign);
}

// Round 3
// 362.217 us; speedup vs baseline: 1.0503x; 1.0503x over previous
//
#include <hip/hip_runtime.h>
#include <math.h>

#define NG 300
#define NP 100000
#define NC 80
#define PRED_COLS 85   // 5 + NC
#define ALPHA_C 0.75f
#define BETA_C  1.0f
#define EPS_C   1e-7f
#define TPB 256
#define BCH 8                 // top-k chunks per gt row
#define CHUNK (NP / BCH)      // 12500
#define KCAP 10
#define NSLAB 4               // gt slabs for cost kernel occupancy
#define GSLAB (NG / NSLAB)    // 75

// ---------------------------------------------------------------------------
// Kernel A0: probs[c][p] = sigmoid(preds[p][5+c]).  Class-major layout so the
// cost kernel's per-g prob read is a coalesced 256B/wave stream.
// Per-lane row walk is L1-resident (64 rows x 340B = 21.8KB < 32KB L1).
// ---------------------------------------------------------------------------
__global__ __launch_bounds__(TPB) void sigmoid_kernel(
    const float* __restrict__ preds, float* __restrict__ probs)
{
    int p = blockIdx.x * TPB + threadIdx.x;
    if (p >= NP) return;
    const float* row = preds + (size_t)p * PRED_COLS + 5;
#pragma unroll 8
    for (int c = 0; c < NC; ++c) {
        probs[(size_t)c * NP + p] = 1.f / (1.f + expf(-row[c]));
    }
}

// ---------------------------------------------------------------------------
// Kernel A1: cost matrix.  grid = (391 pred-blocks, NSLAB gt-slabs); each
// block: 256 preds x 75 gts.  gt descriptors packed as float4 in LDS
// (broadcast ds_read_b128).  Arithmetic is bitwise-identical to the round-2
// passing kernel (same divides, same expf) -- structure-only change.
// ---------------------------------------------------------------------------
template <bool USE_PROBS>
__global__ __launch_bounds__(TPB) void cost_kernel(
    const float* __restrict__ preds, const float* __restrict__ gt_boxes,
    const int* __restrict__ gt_classes, float* __restrict__ cost,
    const float* __restrict__ probs)
{
    __shared__ float4 sbox[GSLAB];   // gx1, gy1, gx2, gy2
    __shared__ float4 smisc[GSLAB];  // area_g, gcx, gcy, atan_g
    __shared__ int    scls[GSLAB];   // class (false path) or class*NP (true path)

    const int g0 = blockIdx.y * GSLAB;

    for (int i = threadIdx.x; i < GSLAB; i += TPB) {
        int g = g0 + i;
        float4 b = ((const float4*)gt_boxes)[g];
        float x1 = b.x, y1 = b.y, x2 = b.z, y2 = b.w;
        sbox[i] = b;
        float4 m;
        m.x = fmaxf(x2 - x1, 0.f) * fmaxf(y2 - y1, 0.f);
        m.y = (x1 + x2) * 0.5f;
        m.z = (y1 + y2) * 0.5f;
        m.w = atanf(fmaxf(x2 - x1, EPS_C) / fmaxf(y2 - y1, EPS_C));
        smisc[i] = m;
        scls[i] = USE_PROBS ? gt_classes[g] * NP : gt_classes[g];
    }
    __syncthreads();

    int p = blockIdx.x * TPB + threadIdx.x;
    if (p >= NP) return;

    const float* row = preds + (size_t)p * PRED_COLS;
    float xc = row[0], yc = row[1], w = row[2], h = row[3];
    float px1 = xc - w * 0.5f, py1 = yc - h * 0.5f;
    float px2 = xc + w * 0.5f, py2 = yc + h * 0.5f;
    float areap = fmaxf(px2 - px1, 0.f) * fmaxf(py2 - py1, 0.f);
    float pcx = (px1 + px2) * 0.5f, pcy = (py1 + py2) * 0.5f;
    float atp = atanf(fmaxf(px2 - px1, EPS_C) / fmaxf(py2 - py1, EPS_C));

    const float VC = (float)(4.0 / (M_PI * M_PI));
    float* out = cost + (size_t)g0 * NP + p;

#pragma unroll 5
    for (int i = 0; i < GSLAB; ++i) {
        float4 b = sbox[i];
        float4 m = smisc[i];
        float gx1 = b.x, gy1 = b.y, gx2 = b.z, gy2 = b.w;
        float xx1 = fmaxf(px1, gx1), yy1 = fmaxf(py1, gy1);
        float xx2 = fminf(px2, gx2), yy2 = fminf(py2, gy2);
        float inter = fmaxf(xx2 - xx1, 0.f) * fmaxf(yy2 - yy1, 0.f);
        float uni = areap + m.x - inter + EPS_C;
        float iou = inter / uni;
        float dx = pcx - m.y, dy = pcy - m.z;
        float cd2 = dx * dx + dy * dy;
        float cw = fmaxf(fmaxf(px2, gx2) - fminf(px1, gx1), EPS_C);
        float ch = fmaxf(fmaxf(py2, gy2) - fminf(py1, gy1), EPS_C);
        float c2 = cw * cw + ch * ch + EPS_C;
        float dat = m.w - atp;
        float v = VC * dat * dat;
        float alpha_t = v / (1.f - iou + v + EPS_C);
        float ciou = iou - cd2 / c2 - alpha_t * v;

        float prob;
        if (USE_PROBS) {
            prob = probs[(size_t)scls[i] + p];
        } else {
            prob = 1.f / (1.f + expf(-row[5 + scls[i]]));
        }
        float cst = ALPHA_C * (1.f - prob) +
                    BETA_C * (1.f - fminf(fmaxf(ciou, 0.f), 1.f));
        out[(size_t)i * NP] = cst;
    }
}

// ---------------------------------------------------------------------------
// Kernel B: partial top-10 per (gt, chunk).  float4 scan, register top-10 with
// fully-unrolled static-index insertion, LDS merge tree.  Comparator is
// (cost asc, idx asc) lexicographic == jax.lax.top_k tie-breaking.
// ---------------------------------------------------------------------------
__global__ __launch_bounds__(TPB) void topk_partial(
    const float* __restrict__ cost, float* __restrict__ lc, int* __restrict__ li)
{
    int g  = blockIdx.x / BCH;
    int ch = blockIdx.x % BCH;
    const float* base = cost + (size_t)g * NP + (size_t)ch * CHUNK;

    float c[KCAP]; int id[KCAP];
#pragma unroll
    for (int k = 0; k < KCAP; ++k) { c[k] = INFINITY; id[k] = 0x7fffffff; }

    const float4* b4 = (const float4*)base;
    const int NV = CHUNK / 4;  // 3125
    for (int i = threadIdx.x; i < NV; i += TPB) {
        float4 v = b4[i];
        int pbase = ch * CHUNK + i * 4;
        float vv[4] = {v.x, v.y, v.z, v.w};
#pragma unroll
        for (int q = 0; q < 4; ++q) {
            float val = vv[q];
            if (val < c[KCAP - 1]) {  // ties excluded: existing has smaller idx
#pragma unroll
                for (int j = KCAP - 1; j >= 0; --j) {
                    bool lt = (val < c[j]);
                    if (lt) {
                        bool ltm = (j > 0) && (val < c[j - 1]);
                        if (ltm) { c[j] = c[j - 1]; id[j] = id[j - 1]; }
                        else     { c[j] = val;      id[j] = pbase + q; }
                    }
                }
            }
        }
    }

    __shared__ float sc[TPB][KCAP];
    __shared__ int   si[TPB][KCAP];
    int t = threadIdx.x;
#pragma unroll
    for (int k = 0; k < KCAP; ++k) { sc[t][k] = c[k]; si[t][k] = id[k]; }
    __syncthreads();

    for (int stride = TPB / 2; stride >= 1; stride >>= 1) {
        if (t < stride) {
            int ia = 0, ib = 0;
            float rc[KCAP]; int ri[KCAP];
#pragma unroll
            for (int k = 0; k < KCAP; ++k) {
                float ca = sc[t][ia], cb = sc[t + stride][ib];
                int   ja = si[t][ia], jb = si[t + stride][ib];
                bool ta = (ca < cb) || (ca == cb && ja < jb);
                rc[k] = ta ? ca : cb; ri[k] = ta ? ja : jb;
                ia += ta ? 1 : 0; ib += ta ? 0 : 1;
            }
#pragma unroll
            for (int k = 0; k < KCAP; ++k) { sc[t][k] = rc[k]; si[t][k] = ri[k]; }
        }
        __syncthreads();
    }

    if (t == 0) {
        float* oc = lc + ((size_t)g * BCH + ch) * KCAP;
        int*   oi = li + ((size_t)g * BCH + ch) * KCAP;
#pragma unroll
        for (int k = 0; k < KCAP; ++k) { oc[k] = sc[0][k]; oi[k] = si[0][k]; }
    }
}

// ---------------------------------------------------------------------------
// Kernel C: merge the 8 partial lists per gt, compute Kt from the epoch
// schedule (banker's rounding, matching Python round()), write assignments.
// ---------------------------------------------------------------------------
__global__ __launch_bounds__(64) void topk_final(
    const float* __restrict__ lc, const int* __restrict__ li,
    const int* __restrict__ epoch, const int* __restrict__ total_epochs,
    float* __restrict__ out_assign)
{
    int g = blockIdx.x;
    __shared__ float sc[BCH * KCAP];
    __shared__ int   si[BCH * KCAP];
    for (int i = threadIdx.x; i < BCH * KCAP; i += 64) {
        sc[i] = lc[(size_t)g * BCH * KCAP + i];
        si[i] = li[(size_t)g * BCH * KCAP + i];
    }
    __syncthreads();

    if (threadIdx.x == 0) {
        int ep = epoch[0], te = total_epochs[0];
        int denom = te - 1; if (denom < 1) denom = 1;
        double tt = (double)ep / (double)denom;
        double val = 10.0 - 9.0 * tt;
        int K = (int)rint(val);
        if (K < 1) K = 1; if (K > 10) K = 10;
        int Kt = (K < NP) ? K : NP;

        for (int k = 0; k < Kt; ++k) {
            float bc = INFINITY; int bi = 0x7fffffff; int bpos = 0;
            for (int j = 0; j < BCH * KCAP; ++j) {
                float cc = sc[j]; int ii = si[j];
                if (cc < bc || (cc == bc && ii < bi)) { bc = cc; bi = ii; bpos = j; }
            }
            sc[bpos] = INFINITY; si[bpos] = 0x7fffffff;
            out_assign[2 * ((size_t)g * Kt + k) + 0] = (float)bi;
            out_assign[2 * ((size_t)g * Kt + k) + 1] = (float)g;
        }
    }
}

// ---------------------------------------------------------------------------
extern "C" void kernel_launch(void* const* d_in, const int* in_sizes, int n_in,
                              void* d_out, int out_size, void* d_ws, size_t ws_size,
                              hipStream_t stream)
{
    const float* preds        = (const float*)d_in[0];
    const float* gt_boxes     = (const float*)d_in[1];
    const int*   gt_classes   = (const int*)d_in[2];
    const int*   epoch        = (const int*)d_in[3];
    const int*   total_epochs = (const int*)d_in[4];

    float* cost       = (float*)d_out;
    float* out_assign = cost + (size_t)NG * NP;

    const int ablocks = (NP + TPB - 1) / TPB;  // 391
    size_t probBytes  = (size_t)NC * NP * sizeof(float);  // 32 MB, [c][p]
    size_t nlist      = (size_t)NG * BCH * KCAP;          // 24000

    char* wsp = (char*)d_ws;
    bool useProbs = ws_size >= probBytes + nlist * 8;
    float* probs; float* lc; int* li;
    if (useProbs) {
        probs = (float*)wsp;
        lc    = (float*)(wsp + probBytes);
        li    = (int*)  (wsp + probBytes + nlist * sizeof(float));
    } else {
        probs = nullptr;
        lc    = (float*)wsp;
        li    = (int*)  (wsp + nlist * sizeof(float));
    }

    if (useProbs) {
        sigmoid_kernel<<<ablocks, TPB, 0, stream>>>(preds, probs);
        cost_kernel<true ><<<dim3(ablocks, NSLAB), TPB, 0, stream>>>(
            preds, gt_boxes, gt_classes, cost, probs);
    } else {
        cost_kernel<false><<<dim3(ablocks, NSLAB), TPB, 0, stream>>>(
            preds, gt_boxes, gt_classes, cost, probs);
    }

    topk_partial<<<NG * BCH, TPB, 0, stream>>>(cost, lc, li);
    topk_final<<<NG, 64, 0, stream>>>(lc, li, epoch, total_epochs, out_assign);
}

// Round 4
// 349.126 us; speedup vs baseline: 1.0897x; 1.0375x over previous
//
#include <hip/hip_runtime.h>
#include <math.h>

#define NG 300
#define NP 100000
#define NC 80
#define PRED_COLS 85   // 5 + NC
#define ALPHA_C 0.75f
#define BETA_C  1.0f
#define EPS_C   1e-7f
#define TPB 256
#define BCH 8                 // top-k chunks per gt row
#define CHUNK (NP / BCH)      // 12500
#define KCAP 10
#define NSLAB 10              // gt slabs for cost kernel occupancy
#define GSLAB (NG / NSLAB)    // 30
#define CTILE 16              // classes per sigmoid block
#define NCT (NC / CTILE)      // 5

__device__ __forceinline__ float fast_rcp(float x) {
    return __builtin_amdgcn_rcpf(x);
}

// ---------------------------------------------------------------------------
// Kernel A0: probs[c][p] = sigmoid(preds[p][5+c]).  Class-major layout so the
// cost kernel's per-g prob read is a coalesced 256B/wave stream.
// grid = (391 pred-blocks, 5 class-tiles) for occupancy.
// ---------------------------------------------------------------------------
__global__ __launch_bounds__(TPB) void sigmoid_kernel(
    const float* __restrict__ preds, float* __restrict__ probs)
{
    int p = blockIdx.x * TPB + threadIdx.x;
    if (p >= NP) return;
    int c0 = blockIdx.y * CTILE;
    const float* row = preds + (size_t)p * PRED_COLS + 5 + c0;
#pragma unroll
    for (int j = 0; j < CTILE; ++j) {
        float l = row[j];
        probs[(size_t)(c0 + j) * NP + p] = fast_rcp(1.f + expf(-l));
    }
}

// ---------------------------------------------------------------------------
// Kernel A1: cost matrix.  grid = (391 pred-blocks, NSLAB gt-slabs); each
// block: 256 preds x 30 gts.  gt descriptors packed as float4 in LDS
// (broadcast ds_read_b128).  Divides via v_rcp_f32 (+~1e-7 rel err, well
// inside the 0.0078 tolerance that already passes).
// ---------------------------------------------------------------------------
template <bool USE_PROBS>
__global__ __launch_bounds__(TPB) void cost_kernel(
    const float* __restrict__ preds, const float* __restrict__ gt_boxes,
    const int* __restrict__ gt_classes, float* __restrict__ cost,
    const float* __restrict__ probs)
{
    __shared__ float4 sbox[GSLAB];   // gx1, gy1, gx2, gy2
    __shared__ float4 smisc[GSLAB];  // area_g, gcx, gcy, atan_g
    __shared__ int    scls[GSLAB];   // class*NP (true path) or class (false)

    const int g0 = blockIdx.y * GSLAB;

    for (int i = threadIdx.x; i < GSLAB; i += TPB) {
        int g = g0 + i;
        float4 b = ((const float4*)gt_boxes)[g];
        float x1 = b.x, y1 = b.y, x2 = b.z, y2 = b.w;
        sbox[i] = b;
        float4 m;
        m.x = fmaxf(x2 - x1, 0.f) * fmaxf(y2 - y1, 0.f);
        m.y = (x1 + x2) * 0.5f;
        m.z = (y1 + y2) * 0.5f;
        m.w = atanf(fmaxf(x2 - x1, EPS_C) / fmaxf(y2 - y1, EPS_C));
        smisc[i] = m;
        scls[i] = USE_PROBS ? gt_classes[g] * NP : gt_classes[g];
    }
    __syncthreads();

    int p = blockIdx.x * TPB + threadIdx.x;
    if (p >= NP) return;

    const float* row = preds + (size_t)p * PRED_COLS;
    float xc = row[0], yc = row[1], w = row[2], h = row[3];
    float px1 = xc - w * 0.5f, py1 = yc - h * 0.5f;
    float px2 = xc + w * 0.5f, py2 = yc + h * 0.5f;
    float areap = fmaxf(px2 - px1, 0.f) * fmaxf(py2 - py1, 0.f);
    float pcx = (px1 + px2) * 0.5f, pcy = (py1 + py2) * 0.5f;
    float atp = atanf(fmaxf(px2 - px1, EPS_C) / fmaxf(py2 - py1, EPS_C));

    const float VC = (float)(4.0 / (M_PI * M_PI));
    float* out = cost + (size_t)g0 * NP + p;

#pragma unroll 6
    for (int i = 0; i < GSLAB; ++i) {
        float4 b = sbox[i];
        float4 m = smisc[i];
        float gx1 = b.x, gy1 = b.y, gx2 = b.z, gy2 = b.w;
        float xx1 = fmaxf(px1, gx1), yy1 = fmaxf(py1, gy1);
        float xx2 = fminf(px2, gx2), yy2 = fminf(py2, gy2);
        float inter = fmaxf(xx2 - xx1, 0.f) * fmaxf(yy2 - yy1, 0.f);
        float uni = areap + m.x - inter + EPS_C;
        float iou = inter * fast_rcp(uni);
        float dx = pcx - m.y, dy = pcy - m.z;
        float cd2 = dx * dx + dy * dy;
        float cw = fmaxf(fmaxf(px2, gx2) - fminf(px1, gx1), EPS_C);
        float ch = fmaxf(fmaxf(py2, gy2) - fminf(py1, gy1), EPS_C);
        float c2 = cw * cw + ch * ch + EPS_C;
        float dat = m.w - atp;
        float v = VC * dat * dat;
        float alpha_t = v * fast_rcp(1.f - iou + v + EPS_C);
        float ciou = iou - cd2 * fast_rcp(c2) - alpha_t * v;

        float prob;
        if (USE_PROBS) {
            prob = probs[(size_t)scls[i] + p];
        } else {
            prob = fast_rcp(1.f + expf(-row[5 + scls[i]]));
        }
        float cst = ALPHA_C * (1.f - prob) +
                    BETA_C * (1.f - fminf(fmaxf(ciou, 0.f), 1.f));
        out[(size_t)i * NP] = cst;
    }
}

// ---------------------------------------------------------------------------
// Kernel B: partial top-10 per (gt, chunk).  float4 scan, register top-10 with
// fully-unrolled static-index insertion, LDS merge tree.  Comparator is
// (cost asc, idx asc) lexicographic == jax.lax.top_k tie-breaking.
// ---------------------------------------------------------------------------
__global__ __launch_bounds__(TPB) void topk_partial(
    const float* __restrict__ cost, float* __restrict__ lc, int* __restrict__ li)
{
    int g  = blockIdx.x / BCH;
    int ch = blockIdx.x % BCH;
    const float* base = cost + (size_t)g * NP + (size_t)ch * CHUNK;

    float c[KCAP]; int id[KCAP];
#pragma unroll
    for (int k = 0; k < KCAP; ++k) { c[k] = INFINITY; id[k] = 0x7fffffff; }

    const float4* b4 = (const float4*)base;
    const int NV = CHUNK / 4;  // 3125
    for (int i = threadIdx.x; i < NV; i += TPB) {
        float4 v = b4[i];
        int pbase = ch * CHUNK + i * 4;
        float vv[4] = {v.x, v.y, v.z, v.w};
#pragma unroll
        for (int q = 0; q < 4; ++q) {
            float val = vv[q];
            if (val < c[KCAP - 1]) {  // ties excluded: existing has smaller idx
#pragma unroll
                for (int j = KCAP - 1; j >= 0; --j) {
                    bool lt = (val < c[j]);
                    if (lt) {
                        bool ltm = (j > 0) && (val < c[j - 1]);
                        if (ltm) { c[j] = c[j - 1]; id[j] = id[j - 1]; }
                        else     { c[j] = val;      id[j] = pbase + q; }
                    }
                }
            }
        }
    }

    __shared__ float sc[TPB][KCAP];
    __shared__ int   si[TPB][KCAP];
    int t = threadIdx.x;
#pragma unroll
    for (int k = 0; k < KCAP; ++k) { sc[t][k] = c[k]; si[t][k] = id[k]; }
    __syncthreads();

    for (int stride = TPB / 2; stride >= 1; stride >>= 1) {
        if (t < stride) {
            int ia = 0, ib = 0;
            float rc[KCAP]; int ri[KCAP];
#pragma unroll
            for (int k = 0; k < KCAP; ++k) {
                float ca = sc[t][ia], cb = sc[t + stride][ib];
                int   ja = si[t][ia], jb = si[t + stride][ib];
                bool ta = (ca < cb) || (ca == cb && ja < jb);
                rc[k] = ta ? ca : cb; ri[k] = ta ? ja : jb;
                ia += ta ? 1 : 0; ib += ta ? 0 : 1;
            }
#pragma unroll
            for (int k = 0; k < KCAP; ++k) { sc[t][k] = rc[k]; si[t][k] = ri[k]; }
        }
        __syncthreads();
    }

    if (t == 0) {
        float* oc = lc + ((size_t)g * BCH + ch) * KCAP;
        int*   oi = li + ((size_t)g * BCH + ch) * KCAP;
#pragma unroll
        for (int k = 0; k < KCAP; ++k) { oc[k] = sc[0][k]; oi[k] = si[0][k]; }
    }
}

// ---------------------------------------------------------------------------
// Kernel C: merge the 8 partial lists per gt, compute Kt from the epoch
// schedule (banker's rounding, matching Python round()), write assignments.
// ---------------------------------------------------------------------------
__global__ __launch_bounds__(64) void topk_final(
    const float* __restrict__ lc, const int* __restrict__ li,
    const int* __restrict__ epoch, const int* __restrict__ total_epochs,
    float* __restrict__ out_assign)
{
    int g = blockIdx.x;
    __shared__ float sc[BCH * KCAP];
    __shared__ int   si[BCH * KCAP];
    for (int i = threadIdx.x; i < BCH * KCAP; i += 64) {
        sc[i] = lc[(size_t)g * BCH * KCAP + i];
        si[i] = li[(size_t)g * BCH * KCAP + i];
    }
    __syncthreads();

    if (threadIdx.x == 0) {
        int ep = epoch[0], te = total_epochs[0];
        int denom = te - 1; if (denom < 1) denom = 1;
        double tt = (double)ep / (double)denom;
        double val = 10.0 - 9.0 * tt;
        int K = (int)rint(val);
        if (K < 1) K = 1; if (K > 10) K = 10;
        int Kt = (K < NP) ? K : NP;

        for (int k = 0; k < Kt; ++k) {
            float bc = INFINITY; int bi = 0x7fffffff; int bpos = 0;
            for (int j = 0; j < BCH * KCAP; ++j) {
                float cc = sc[j]; int ii = si[j];
                if (cc < bc || (cc == bc && ii < bi)) { bc = cc; bi = ii; bpos = j; }
            }
            sc[bpos] = INFINITY; si[bpos] = 0x7fffffff;
            out_assign[2 * ((size_t)g * Kt + k) + 0] = (float)bi;
            out_assign[2 * ((size_t)g * Kt + k) + 1] = (float)g;
        }
    }
}

// ---------------------------------------------------------------------------
extern "C" void kernel_launch(void* const* d_in, const int* in_sizes, int n_in,
                              void* d_out, int out_size, void* d_ws, size_t ws_size,
                              hipStream_t stream)
{
    const float* preds        = (const float*)d_in[0];
    const float* gt_boxes     = (const float*)d_in[1];
    const int*   gt_classes   = (const int*)d_in[2];
    const int*   epoch        = (const int*)d_in[3];
    const int*   total_epochs = (const int*)d_in[4];

    float* cost       = (float*)d_out;
    float* out_assign = cost + (size_t)NG * NP;

    const int ablocks = (NP + TPB - 1) / TPB;  // 391
    size_t probBytes  = (size_t)NC * NP * sizeof(float);  // 32 MB, [c][p]
    size_t nlist      = (size_t)NG * BCH * KCAP;          // 24000

    char* wsp = (char*)d_ws;
    bool useProbs = ws_size >= probBytes + nlist * 8;
    float* probs; float* lc; int* li;
    if (useProbs) {
        probs = (float*)wsp;
        lc    = (float*)(wsp + probBytes);
        li    = (int*)  (wsp + probBytes + nlist * sizeof(float));
    } else {
        probs = nullptr;
        lc    = (float*)wsp;
        li    = (int*)  (wsp + nlist * sizeof(float));
    }

    if (useProbs) {
        sigmoid_kernel<<<dim3(ablocks, NCT), TPB, 0, stream>>>(preds, probs);
        cost_kernel<true ><<<dim3(ablocks, NSLAB), TPB, 0, stream>>>(
            preds, gt_boxes, gt_classes, cost, probs);
    } else {
        cost_kernel<false><<<dim3(ablocks, NSLAB), TPB, 0, stream>>>(
            preds, gt_boxes, gt_classes, cost, probs);
    }

    topk_partial<<<NG * BCH, TPB, 0, stream>>>(cost, lc, li);
    topk_final<<<NG, 64, 0, stream>>>(lc, li, epoch, total_epochs, out_assign);
}

// Round 5
// 334.552 us; speedup vs baseline: 1.1372x; 1.0436x over previous
//
#include <hip/hip_runtime.h>
#include <math.h>

#define NG 300
#define NP 100000
#define NC 80
#define PRED_COLS 85   // 5 + NC
#define ALPHA_C 0.75f
#define BETA_C  1.0f
#define EPS_C   1e-7f
#define TPB 256
#define BCH 8                 // top-k chunks per gt row
#define CHUNK (NP / BCH)      // 12500
#define KCAP 10
#define NSLAB 10              // gt slabs for cost kernel occupancy
#define GSLAB (NG / NSLAB)    // 30
#define CTILE 16              // classes per sigmoid block
#define NCT (NC / CTILE)      // 5

__device__ __forceinline__ float fast_rcp(float x) {
    return __builtin_amdgcn_rcpf(x);
}

// ---------------------------------------------------------------------------
// Kernel A0: probs[c][p] = sigmoid(preds[p][5+c]).  Class-major layout so the
// cost kernel's per-g prob read is a coalesced 256B/wave stream.
// ---------------------------------------------------------------------------
__global__ __launch_bounds__(TPB) void sigmoid_kernel(
    const float* __restrict__ preds, float* __restrict__ probs)
{
    int p = blockIdx.x * TPB + threadIdx.x;
    if (p >= NP) return;
    int c0 = blockIdx.y * CTILE;
    const float* row = preds + (size_t)p * PRED_COLS + 5 + c0;
#pragma unroll
    for (int j = 0; j < CTILE; ++j) {
        float l = row[j];
        probs[(size_t)(c0 + j) * NP + p] = fast_rcp(1.f + expf(-l));
    }
}

// ---------------------------------------------------------------------------
// Kernel A1: cost matrix.  grid = (391 pred-blocks, NSLAB gt-slabs); each
// block: 256 preds x 30 gts.  gt descriptors packed as float4 in LDS.
// Divides via v_rcp_f32 (validated: absmax unchanged at 0.0078 in R4).
// ---------------------------------------------------------------------------
template <bool USE_PROBS>
__global__ __launch_bounds__(TPB) void cost_kernel(
    const float* __restrict__ preds, const float* __restrict__ gt_boxes,
    const int* __restrict__ gt_classes, float* __restrict__ cost,
    const float* __restrict__ probs)
{
    __shared__ float4 sbox[GSLAB];   // gx1, gy1, gx2, gy2
    __shared__ float4 smisc[GSLAB];  // area_g, gcx, gcy, atan_g
    __shared__ int    scls[GSLAB];   // class*NP (true path) or class (false)

    const int g0 = blockIdx.y * GSLAB;

    for (int i = threadIdx.x; i < GSLAB; i += TPB) {
        int g = g0 + i;
        float4 b = ((const float4*)gt_boxes)[g];
        float x1 = b.x, y1 = b.y, x2 = b.z, y2 = b.w;
        sbox[i] = b;
        float4 m;
        m.x = fmaxf(x2 - x1, 0.f) * fmaxf(y2 - y1, 0.f);
        m.y = (x1 + x2) * 0.5f;
        m.z = (y1 + y2) * 0.5f;
        m.w = atanf(fmaxf(x2 - x1, EPS_C) / fmaxf(y2 - y1, EPS_C));
        smisc[i] = m;
        scls[i] = USE_PROBS ? gt_classes[g] * NP : gt_classes[g];
    }
    __syncthreads();

    int p = blockIdx.x * TPB + threadIdx.x;
    if (p >= NP) return;

    const float* row = preds + (size_t)p * PRED_COLS;
    float xc = row[0], yc = row[1], w = row[2], h = row[3];
    float px1 = xc - w * 0.5f, py1 = yc - h * 0.5f;
    float px2 = xc + w * 0.5f, py2 = yc + h * 0.5f;
    float areap = fmaxf(px2 - px1, 0.f) * fmaxf(py2 - py1, 0.f);
    float pcx = (px1 + px2) * 0.5f, pcy = (py1 + py2) * 0.5f;
    float atp = atanf(fmaxf(px2 - px1, EPS_C) / fmaxf(py2 - py1, EPS_C));

    const float VC = (float)(4.0 / (M_PI * M_PI));
    float* out = cost + (size_t)g0 * NP + p;

#pragma unroll 6
    for (int i = 0; i < GSLAB; ++i) {
        float4 b = sbox[i];
        float4 m = smisc[i];
        float gx1 = b.x, gy1 = b.y, gx2 = b.z, gy2 = b.w;
        float xx1 = fmaxf(px1, gx1), yy1 = fmaxf(py1, gy1);
        float xx2 = fminf(px2, gx2), yy2 = fminf(py2, gy2);
        float inter = fmaxf(xx2 - xx1, 0.f) * fmaxf(yy2 - yy1, 0.f);
        float uni = areap + m.x - inter + EPS_C;
        float iou = inter * fast_rcp(uni);
        float dx = pcx - m.y, dy = pcy - m.z;
        float cd2 = dx * dx + dy * dy;
        float cw = fmaxf(fmaxf(px2, gx2) - fminf(px1, gx1), EPS_C);
        float ch = fmaxf(fmaxf(py2, gy2) - fminf(py1, gy1), EPS_C);
        float c2 = cw * cw + ch * ch + EPS_C;
        float dat = m.w - atp;
        float v = VC * dat * dat;
        float alpha_t = v * fast_rcp(1.f - iou + v + EPS_C);
        float ciou = iou - cd2 * fast_rcp(c2) - alpha_t * v;

        float prob;
        if (USE_PROBS) {
            prob = probs[(size_t)scls[i] + p];
        } else {
            prob = fast_rcp(1.f + expf(-row[5 + scls[i]]));
        }
        float cst = ALPHA_C * (1.f - prob) +
                    BETA_C * (1.f - fminf(fmaxf(ciou, 0.f), 1.f));
        out[(size_t)i * NP] = cst;
    }
}

// ---------------------------------------------------------------------------
// Kernel B: partial top-10 per (gt, chunk) -- wave-cooperative.
// The wave shares one sorted 10-list held in lanes 0..9's registers.
// Prefilter: ballot(vmin <= thr); candidates serialized via ffs over the
// ballot mask; insertion = lexicographic-position popcount + shfl_up shift.
// Order-independent and exactly jax.lax.top_k tie-compatible:
//  - reject only when cv > thr (cv strictly follows all 10 entries; thr is
//    monotonically non-increasing, so the rejection is final-state-correct)
//  - cv == thr enters and the (cost, idx)-lexicographic pos-check decides.
// ---------------------------------------------------------------------------
__global__ __launch_bounds__(TPB) void topk_partial(
    const float* __restrict__ cost, float* __restrict__ lc, int* __restrict__ li)
{
    int g  = blockIdx.x / BCH;
    int ch = blockIdx.x % BCH;
    const float4* b4 = (const float4*)(cost + (size_t)g * NP + (size_t)ch * CHUNK);
    const int NV = CHUNK / 4;  // 3125

    const int lane = threadIdx.x & 63;
    const int wid  = threadIdx.x >> 6;

    float ev = INFINITY;       // this lane's list entry (valid for lane < 10)
    int   ei = 0x7fffffff;
    float thr = INFINITY;      // wave-uniform 10th-best

    for (int i = threadIdx.x; i < NV; i += TPB) {
        float4 v = b4[i];
        int ib = ch * CHUNK + i * 4;   // this lane's element base index
        float vmin = fminf(fminf(v.x, v.y), fminf(v.z, v.w));
        if (__ballot(vmin <= thr) == 0ull) continue;

        float vq[4] = {v.x, v.y, v.z, v.w};
#pragma unroll
        for (int q = 0; q < 4; ++q) {
            unsigned long long m = __ballot(vq[q] <= thr);
            while (m) {
                int l = __ffsll(m) - 1;
                m &= m - 1;
                float cv = __shfl(vq[q], l);
                int   ci = __shfl(ib, l) + q;
                if (!(cv <= thr)) continue;   // thr may have tightened
                // lexicographic insertion position
                bool prec = (ev < cv) || (ev == cv && ei < ci);
                unsigned long long bb = __ballot(prec) & 0x3FFull;
                int pos = __popcll(bb);
                if (pos < KCAP) {
                    float pev = __shfl_up(ev, 1);
                    int   pei = __shfl_up(ei, 1);
                    if (lane > pos && lane < KCAP) { ev = pev; ei = pei; }
                    if (lane == pos)               { ev = cv;  ei = ci;  }
                    thr = __shfl(ev, KCAP - 1);
                }
            }
        }
    }

    // stash the 4 wave lists, merge on thread 0 (40 entries, trivial)
    __shared__ float swv[4][KCAP];
    __shared__ int   swi[4][KCAP];
    if (lane < KCAP) { swv[wid][lane] = ev; swi[wid][lane] = ei; }
    __syncthreads();

    if (threadIdx.x == 0) {
        int hp[4] = {0, 0, 0, 0};
        float* oc = lc + ((size_t)g * BCH + ch) * KCAP;
        int*   oi = li + ((size_t)g * BCH + ch) * KCAP;
        for (int k = 0; k < KCAP; ++k) {
            float bv = INFINITY; int bi = 0x7fffffff; int bw = -1;
            for (int wv = 0; wv < 4; ++wv) {
                if (hp[wv] >= KCAP) continue;
                float cv = swv[wv][hp[wv]];
                int   ci = swi[wv][hp[wv]];
                if (cv < bv || (cv == bv && ci < bi)) { bv = cv; bi = ci; bw = wv; }
            }
            hp[bw]++;
            oc[k] = bv; oi[k] = bi;
        }
    }
}

// ---------------------------------------------------------------------------
// Kernel C: merge the 8 partial lists per gt, compute Kt from the epoch
// schedule (banker's rounding, matching Python round()), write assignments.
// ---------------------------------------------------------------------------
__global__ __launch_bounds__(64) void topk_final(
    const float* __restrict__ lc, const int* __restrict__ li,
    const int* __restrict__ epoch, const int* __restrict__ total_epochs,
    float* __restrict__ out_assign)
{
    int g = blockIdx.x;
    __shared__ float sc[BCH * KCAP];
    __shared__ int   si[BCH * KCAP];
    for (int i = threadIdx.x; i < BCH * KCAP; i += 64) {
        sc[i] = lc[(size_t)g * BCH * KCAP + i];
        si[i] = li[(size_t)g * BCH * KCAP + i];
    }
    __syncthreads();

    if (threadIdx.x == 0) {
        int ep = epoch[0], te = total_epochs[0];
        int denom = te - 1; if (denom < 1) denom = 1;
        double tt = (double)ep / (double)denom;
        double val = 10.0 - 9.0 * tt;
        int K = (int)rint(val);
        if (K < 1) K = 1; if (K > 10) K = 10;
        int Kt = (K < NP) ? K : NP;

        for (int k = 0; k < Kt; ++k) {
            float bc = INFINITY; int bi = 0x7fffffff; int bpos = 0;
            for (int j = 0; j < BCH * KCAP; ++j) {
                float cc = sc[j]; int ii = si[j];
                if (cc < bc || (cc == bc && ii < bi)) { bc = cc; bi = ii; bpos = j; }
            }
            sc[bpos] = INFINITY; si[bpos] = 0x7fffffff;
            out_assign[2 * ((size_t)g * Kt + k) + 0] = (float)bi;
            out_assign[2 * ((size_t)g * Kt + k) + 1] = (float)g;
        }
    }
}

// ---------------------------------------------------------------------------
extern "C" void kernel_launch(void* const* d_in, const int* in_sizes, int n_in,
                              void* d_out, int out_size, void* d_ws, size_t ws_size,
                              hipStream_t stream)
{
    const float* preds        = (const float*)d_in[0];
    const float* gt_boxes     = (const float*)d_in[1];
    const int*   gt_classes   = (const int*)d_in[2];
    const int*   epoch        = (const int*)d_in[3];
    const int*   total_epochs = (const int*)d_in[4];

    float* cost       = (float*)d_out;
    float* out_assign = cost + (size_t)NG * NP;

    const int ablocks = (NP + TPB - 1) / TPB;  // 391
    size_t probBytes  = (size_t)NC * NP * sizeof(float);  // 32 MB, [c][p]
    size_t nlist      = (size_t)NG * BCH * KCAP;          // 24000

    char* wsp = (char*)d_ws;
    bool useProbs = ws_size >= probBytes + nlist * 8;
    float* probs; float* lc; int* li;
    if (useProbs) {
        probs = (float*)wsp;
        lc    = (float*)(wsp + probBytes);
        li    = (int*)  (wsp + probBytes + nlist * sizeof(float));
    } else {
        probs = nullptr;
        lc    = (float*)wsp;
        li    = (int*)  (wsp + nlist * sizeof(float));
    }

    if (useProbs) {
        sigmoid_kernel<<<dim3(ablocks, NCT), TPB, 0, stream>>>(preds, probs);
        cost_kernel<true ><<<dim3(ablocks, NSLAB), TPB, 0, stream>>>(
            preds, gt_boxes, gt_classes, cost, probs);
    } else {
        cost_kernel<false><<<dim3(ablocks, NSLAB), TPB, 0, stream>>>(
            preds, gt_boxes, gt_classes, cost, probs);
    }

    topk_partial<<<NG * BCH, TPB, 0, stream>>>(cost, lc, li);
    topk_final<<<NG, 64, 0, stream>>>(lc, li, epoch, total_epochs, out_assign);
}

// Round 6
// 270.012 us; speedup vs baseline: 1.4090x; 1.2390x over previous
//
#include <hip/hip_runtime.h>
#include <math.h>

#define NG 300
#define NP 100000
#define NC 80
#define PRED_COLS 85   // 5 + NC
#define ALPHA_C 0.75f
#define BETA_C  1.0f
#define EPS_C   1e-7f
#define TPB 256
#define BCH 10                // top-k chunks per gt row
#define CHUNK (NP / BCH)      // 10000
#define KCAP 10
#define NSLAB 20              // gt slabs for cost kernel occupancy
#define GSLAB (NG / NSLAB)    // 15
#define CTILE 16              // classes per prep block
#define NCT (NC / CTILE)      // 5

__device__ __forceinline__ float fast_rcp(float x) {
    return __builtin_amdgcn_rcpf(x);
}

// ---------------------------------------------------------------------------
// Kernel P: prep.  blockIdx.y < NCT: probs[c][p] = sigmoid(logit) for a
// 16-class tile (class-major, so cost kernel reads are coalesced).
// blockIdx.y == NCT: pack per-pred box-derived values into two float4 arrays
// (kills the 16B-used-of-128B-line preds re-read that cost 50MB+ of HBM/slab).
// ---------------------------------------------------------------------------
__global__ __launch_bounds__(TPB) void prep_kernel(
    const float* __restrict__ preds, float* __restrict__ probs,
    float4* __restrict__ bA, float4* __restrict__ bB)
{
    int p = blockIdx.x * TPB + threadIdx.x;
    if (p >= NP) return;
    if (blockIdx.y < NCT) {
        int c0 = blockIdx.y * CTILE;
        const float* row = preds + (size_t)p * PRED_COLS + 5 + c0;
#pragma unroll
        for (int j = 0; j < CTILE; ++j) {
            float l = row[j];
            probs[(size_t)(c0 + j) * NP + p] = fast_rcp(1.f + expf(-l));
        }
    } else {
        const float* row = preds + (size_t)p * PRED_COLS;
        float xc = row[0], yc = row[1], w = row[2], h = row[3];
        float px1 = xc - w * 0.5f, py1 = yc - h * 0.5f;
        float px2 = xc + w * 0.5f, py2 = yc + h * 0.5f;
        float4 a = {px1, py1, px2, py2};
        float4 b;
        b.x = fmaxf(px2 - px1, 0.f) * fmaxf(py2 - py1, 0.f);
        b.y = (px1 + px2) * 0.5f;
        b.z = (py1 + py2) * 0.5f;
        b.w = atanf(fmaxf(px2 - px1, EPS_C) / fmaxf(py2 - py1, EPS_C));
        bA[p] = a; bB[p] = b;
    }
}

// ---------------------------------------------------------------------------
// Kernel A: cost matrix.  grid = (391, NSLAB); block = 256 preds x 15 gts.
// Per-thread prologue: 2 coalesced float4 loads.  gt descriptors in LDS.
// Divides via v_rcp_f32 (validated: absmax 0.0078 passing since R4).
// ---------------------------------------------------------------------------
template <bool USE_PACK>
__global__ __launch_bounds__(TPB) void cost_kernel(
    const float* __restrict__ preds, const float* __restrict__ gt_boxes,
    const int* __restrict__ gt_classes, float* __restrict__ cost,
    const float* __restrict__ probs,
    const float4* __restrict__ bA, const float4* __restrict__ bB)
{
    __shared__ float4 sbox[GSLAB];   // gx1, gy1, gx2, gy2
    __shared__ float4 smisc[GSLAB];  // area_g, gcx, gcy, atan_g
    __shared__ int    scls[GSLAB];   // class*NP

    const int g0 = blockIdx.y * GSLAB;

    for (int i = threadIdx.x; i < GSLAB; i += TPB) {
        int g = g0 + i;
        float4 b = ((const float4*)gt_boxes)[g];
        float x1 = b.x, y1 = b.y, x2 = b.z, y2 = b.w;
        sbox[i] = b;
        float4 m;
        m.x = fmaxf(x2 - x1, 0.f) * fmaxf(y2 - y1, 0.f);
        m.y = (x1 + x2) * 0.5f;
        m.z = (y1 + y2) * 0.5f;
        m.w = atanf(fmaxf(x2 - x1, EPS_C) / fmaxf(y2 - y1, EPS_C));
        smisc[i] = m;
        scls[i] = gt_classes[g] * NP;
    }
    __syncthreads();

    int p = blockIdx.x * TPB + threadIdx.x;
    if (p >= NP) return;

    float px1, py1, px2, py2, areap, pcx, pcy, atp;
    if (USE_PACK) {
        float4 a = bA[p], b = bB[p];
        px1 = a.x; py1 = a.y; px2 = a.z; py2 = a.w;
        areap = b.x; pcx = b.y; pcy = b.z; atp = b.w;
    } else {
        const float* row = preds + (size_t)p * PRED_COLS;
        float xc = row[0], yc = row[1], w = row[2], h = row[3];
        px1 = xc - w * 0.5f; py1 = yc - h * 0.5f;
        px2 = xc + w * 0.5f; py2 = yc + h * 0.5f;
        areap = fmaxf(px2 - px1, 0.f) * fmaxf(py2 - py1, 0.f);
        pcx = (px1 + px2) * 0.5f; pcy = (py1 + py2) * 0.5f;
        atp = atanf(fmaxf(px2 - px1, EPS_C) / fmaxf(py2 - py1, EPS_C));
    }

    const float VC = (float)(4.0 / (M_PI * M_PI));
    float* out = cost + (size_t)g0 * NP + p;

#pragma unroll 5
    for (int i = 0; i < GSLAB; ++i) {
        float4 b = sbox[i];
        float4 m = smisc[i];
        float gx1 = b.x, gy1 = b.y, gx2 = b.z, gy2 = b.w;
        float xx1 = fmaxf(px1, gx1), yy1 = fmaxf(py1, gy1);
        float xx2 = fminf(px2, gx2), yy2 = fminf(py2, gy2);
        float inter = fmaxf(xx2 - xx1, 0.f) * fmaxf(yy2 - yy1, 0.f);
        float uni = areap + m.x - inter + EPS_C;
        float iou = inter * fast_rcp(uni);
        float dx = pcx - m.y, dy = pcy - m.z;
        float cd2 = dx * dx + dy * dy;
        float cw = fmaxf(fmaxf(px2, gx2) - fminf(px1, gx1), EPS_C);
        float ch = fmaxf(fmaxf(py2, gy2) - fminf(py1, gy1), EPS_C);
        float c2 = cw * cw + ch * ch + EPS_C;
        float dat = m.w - atp;
        float v = VC * dat * dat;
        float alpha_t = v * fast_rcp(1.f - iou + v + EPS_C);
        float ciou = iou - cd2 * fast_rcp(c2) - alpha_t * v;

        float prob = probs[(size_t)scls[i] + p];
        float cst = ALPHA_C * (1.f - prob) +
                    BETA_C * (1.f - fminf(fmaxf(ciou, 0.f), 1.f));
        out[(size_t)i * NP] = cst;
    }
}

// lexicographic (val, idx) wave-min butterfly; all 64 lanes converge.
__device__ __forceinline__ void wave_lexmin(float& v, int& i) {
#pragma unroll
    for (int off = 32; off >= 1; off >>= 1) {
        float ov = __shfl_xor(v, off);
        int   oi = __shfl_xor(i, off);
        if (ov < v || (ov == v && oi < i)) { v = ov; i = oi; }
    }
}

// ---------------------------------------------------------------------------
// Kernel B: partial top-10 per (gt, chunk) -- wave-cooperative sorted list in
// lanes 0..9, ballot prefilter + shfl insertion (validated R5).  Tail: the 4
// wave lists merge via wave-0 PARALLEL selection (reg-held entries + lex-min
// butterfly), replacing the latency-chained serial thread-0 merge.
// ---------------------------------------------------------------------------
__global__ __launch_bounds__(TPB) void topk_partial(
    const float* __restrict__ cost, float* __restrict__ lc, int* __restrict__ li)
{
    int g  = blockIdx.x / BCH;
    int ch = blockIdx.x % BCH;
    const float4* b4 = (const float4*)(cost + (size_t)g * NP + (size_t)ch * CHUNK);
    const int NV = CHUNK / 4;  // 2500

    const int lane = threadIdx.x & 63;
    const int wid  = threadIdx.x >> 6;

    float ev = INFINITY;       // this lane's list entry (valid for lane < 10)
    int   ei = 0x7fffffff;
    float thr = INFINITY;      // wave-uniform 10th-best

    for (int i = threadIdx.x; i < NV; i += TPB) {
        float4 v = b4[i];
        int ib = ch * CHUNK + i * 4;
        float vmin = fminf(fminf(v.x, v.y), fminf(v.z, v.w));
        if (__ballot(vmin <= thr) == 0ull) continue;

        float vq[4] = {v.x, v.y, v.z, v.w};
#pragma unroll
        for (int q = 0; q < 4; ++q) {
            unsigned long long m = __ballot(vq[q] <= thr);
            while (m) {
                int l = __ffsll(m) - 1;
                m &= m - 1;
                float cv = __shfl(vq[q], l);
                int   ci = __shfl(ib, l) + q;
                if (!(cv <= thr)) continue;   // thr may have tightened
                bool prec = (ev < cv) || (ev == cv && ei < ci);
                unsigned long long bb = __ballot(prec) & 0x3FFull;
                int pos = __popcll(bb);
                if (pos < KCAP) {
                    float pev = __shfl_up(ev, 1);
                    int   pei = __shfl_up(ei, 1);
                    if (lane > pos && lane < KCAP) { ev = pev; ei = pei; }
                    if (lane == pos)               { ev = cv;  ei = ci;  }
                    thr = __shfl(ev, KCAP - 1);
                }
            }
        }
    }

    __shared__ float swv[4 * KCAP];
    __shared__ int   swi[4 * KCAP];
    if (lane < KCAP) { swv[wid * KCAP + lane] = ev; swi[wid * KCAP + lane] = ei; }
    __syncthreads();

    if (wid == 0) {
        float mv = (lane < 4 * KCAP) ? swv[lane] : INFINITY;
        int   mi = (lane < 4 * KCAP) ? swi[lane] : 0x7fffffff;
        float* oc = lc + ((size_t)g * BCH + ch) * KCAP;
        int*   oi = li + ((size_t)g * BCH + ch) * KCAP;
        for (int k = 0; k < KCAP; ++k) {
            float wv = mv; int wi = mi;
            wave_lexmin(wv, wi);
            if (lane == 0) { oc[k] = wv; oi[k] = wi; }
            if (mv == wv && mi == wi) { mv = INFINITY; mi = 0x7fffffff; }
        }
    }
}

// ---------------------------------------------------------------------------
// Kernel C: merge the BCH partial lists per gt (100 entries, 2 per lane),
// wave-parallel selection; Kt from epoch schedule (banker's rounding).
// ---------------------------------------------------------------------------
__global__ __launch_bounds__(64) void topk_final(
    const float* __restrict__ lc, const int* __restrict__ li,
    const int* __restrict__ epoch, const int* __restrict__ total_epochs,
    float* __restrict__ out_assign)
{
    const int NE = BCH * KCAP;  // 100
    int g = blockIdx.x;
    int lane = threadIdx.x;

    float e0 = INFINITY, e1 = INFINITY;
    int   i0 = 0x7fffffff, i1 = 0x7fffffff;
    {
        const float* pc = lc + (size_t)g * NE;
        const int*   pi = li + (size_t)g * NE;
        e0 = pc[lane]; i0 = pi[lane];                      // lanes 0..63
        if (lane < NE - 64) { e1 = pc[lane + 64]; i1 = pi[lane + 64]; }
    }

    int ep = epoch[0], te = total_epochs[0];
    int denom = te - 1; if (denom < 1) denom = 1;
    double tt = (double)ep / (double)denom;
    int K = (int)rint(10.0 - 9.0 * tt);
    if (K < 1) K = 1; if (K > 10) K = 10;
    int Kt = (K < NP) ? K : NP;

    for (int k = 0; k < Kt; ++k) {
        bool sel0 = (e0 < e1) || (e0 == e1 && i0 < i1);
        float wv = sel0 ? e0 : e1;
        int   wi = sel0 ? i0 : i1;
        wave_lexmin(wv, wi);
        if (lane == 0) {
            out_assign[2 * ((size_t)g * Kt + k) + 0] = (float)wi;
            out_assign[2 * ((size_t)g * Kt + k) + 1] = (float)g;
        }
        if (e0 == wv && i0 == wi) { e0 = INFINITY; i0 = 0x7fffffff; }
        if (e1 == wv && i1 == wi) { e1 = INFINITY; i1 = 0x7fffffff; }
    }
}

// ---------------------------------------------------------------------------
extern "C" void kernel_launch(void* const* d_in, const int* in_sizes, int n_in,
                              void* d_out, int out_size, void* d_ws, size_t ws_size,
                              hipStream_t stream)
{
    const float* preds        = (const float*)d_in[0];
    const float* gt_boxes     = (const float*)d_in[1];
    const int*   gt_classes   = (const int*)d_in[2];
    const int*   epoch        = (const int*)d_in[3];
    const int*   total_epochs = (const int*)d_in[4];

    float* cost       = (float*)d_out;
    float* out_assign = cost + (size_t)NG * NP;

    const int ablocks = (NP + TPB - 1) / TPB;  // 391
    size_t probBytes  = (size_t)NC * NP * sizeof(float);   // 32 MB, [c][p]
    size_t packBytes  = (size_t)NP * 8 * sizeof(float);    // 3.2 MB
    size_t listBytes  = (size_t)NG * BCH * KCAP * 8;       // 240 KB

    char* wsp = (char*)d_ws;
    bool usePack = ws_size >= probBytes + packBytes + listBytes;

    float*  probs = (float*)wsp;
    float4* bA    = (float4*)(wsp + probBytes);
    float4* bB    = (float4*)(wsp + probBytes + packBytes / 2);
    float*  lc; int* li;
    if (usePack) {
        lc = (float*)(wsp + probBytes + packBytes);
        li = (int*)  (wsp + probBytes + packBytes + listBytes / 2);
    } else {
        lc = (float*)(wsp + probBytes);
        li = (int*)  (wsp + probBytes + listBytes / 2);
    }

    if (usePack) {
        prep_kernel<<<dim3(ablocks, NCT + 1), TPB, 0, stream>>>(preds, probs, bA, bB);
        cost_kernel<true ><<<dim3(ablocks, NSLAB), TPB, 0, stream>>>(
            preds, gt_boxes, gt_classes, cost, probs, bA, bB);
    } else {
        prep_kernel<<<dim3(ablocks, NCT), TPB, 0, stream>>>(preds, probs, bA, bB);
        cost_kernel<false><<<dim3(ablocks, NSLAB), TPB, 0, stream>>>(
            preds, gt_boxes, gt_classes, cost, probs, bA, bB);
    }

    topk_partial<<<NG * BCH, TPB, 0, stream>>>(cost, lc, li);
    topk_final<<<NG, 64, 0, stream>>>(lc, li, epoch, total_epochs, out_assign);
}

// Round 7
// 251.248 us; speedup vs baseline: 1.5142x; 1.0747x over previous
//
#include <hip/hip_runtime.h>
#include <math.h>

#define NG 300
#define NP 100000
#define NC 80
#define PRED_COLS 85   // 5 + NC
#define ALPHA_C 0.75f
#define BETA_C  1.0f
#define EPS_C   1e-7f
#define TPB 256
#define BCH 10                // top-k chunks per gt row
#define CHUNK (NP / BCH)      // 10000
#define KCAP 10
#define NSLAB 20              // gt slabs for cost kernel occupancy
#define GSLAB (NG / NSLAB)    // 15
#define CTILE 16              // classes per prep block
#define NCT (NC / CTILE)      // 5

__device__ __forceinline__ float fast_rcp(float x) {
    return __builtin_amdgcn_rcpf(x);
}

// ---------------------------------------------------------------------------
// Kernel P: prep.  blockIdx.y < NCT: probs[c][p] = sigmoid(logit) for a
// 16-class tile (class-major).  blockIdx.y == NCT: pack per-pred box-derived
// values into two float4 arrays (kills the strided preds re-read per slab).
// ---------------------------------------------------------------------------
__global__ __launch_bounds__(TPB) void prep_kernel(
    const float* __restrict__ preds, float* __restrict__ probs,
    float4* __restrict__ bA, float4* __restrict__ bB)
{
    int p = blockIdx.x * TPB + threadIdx.x;
    if (p >= NP) return;
    if (blockIdx.y < NCT) {
        int c0 = blockIdx.y * CTILE;
        const float* row = preds + (size_t)p * PRED_COLS + 5 + c0;
#pragma unroll
        for (int j = 0; j < CTILE; ++j) {
            float l = row[j];
            probs[(size_t)(c0 + j) * NP + p] = fast_rcp(1.f + expf(-l));
        }
    } else {
        const float* row = preds + (size_t)p * PRED_COLS;
        float xc = row[0], yc = row[1], w = row[2], h = row[3];
        float px1 = xc - w * 0.5f, py1 = yc - h * 0.5f;
        float px2 = xc + w * 0.5f, py2 = yc + h * 0.5f;
        float4 a = {px1, py1, px2, py2};
        float4 b;
        b.x = fmaxf(px2 - px1, 0.f) * fmaxf(py2 - py1, 0.f);
        b.y = (px1 + px2) * 0.5f;
        b.z = (py1 + py2) * 0.5f;
        b.w = atanf(fmaxf(px2 - px1, EPS_C) / fmaxf(py2 - py1, EPS_C));
        bA[p] = a; bB[p] = b;
    }
}

// ---------------------------------------------------------------------------
// Kernel A: cost matrix.  grid = (391, NSLAB); block = 256 preds x 15 gts.
// Per-thread prologue: 2 coalesced float4 loads.  gt descriptors in LDS.
// Divides via v_rcp_f32 (validated: absmax 0.0078 passing since R4).
// ---------------------------------------------------------------------------
template <bool USE_PACK>
__global__ __launch_bounds__(TPB) void cost_kernel(
    const float* __restrict__ preds, const float* __restrict__ gt_boxes,
    const int* __restrict__ gt_classes, float* __restrict__ cost,
    const float* __restrict__ probs,
    const float4* __restrict__ bA, const float4* __restrict__ bB)
{
    __shared__ float4 sbox[GSLAB];   // gx1, gy1, gx2, gy2
    __shared__ float4 smisc[GSLAB];  // area_g, gcx, gcy, atan_g
    __shared__ int    scls[GSLAB];   // class*NP

    const int g0 = blockIdx.y * GSLAB;

    for (int i = threadIdx.x; i < GSLAB; i += TPB) {
        int g = g0 + i;
        float4 b = ((const float4*)gt_boxes)[g];
        float x1 = b.x, y1 = b.y, x2 = b.z, y2 = b.w;
        sbox[i] = b;
        float4 m;
        m.x = fmaxf(x2 - x1, 0.f) * fmaxf(y2 - y1, 0.f);
        m.y = (x1 + x2) * 0.5f;
        m.z = (y1 + y2) * 0.5f;
        m.w = atanf(fmaxf(x2 - x1, EPS_C) / fmaxf(y2 - y1, EPS_C));
        smisc[i] = m;
        scls[i] = gt_classes[g] * NP;
    }
    __syncthreads();

    int p = blockIdx.x * TPB + threadIdx.x;
    if (p >= NP) return;

    float px1, py1, px2, py2, areap, pcx, pcy, atp;
    if (USE_PACK) {
        float4 a = bA[p], b = bB[p];
        px1 = a.x; py1 = a.y; px2 = a.z; py2 = a.w;
        areap = b.x; pcx = b.y; pcy = b.z; atp = b.w;
    } else {
        const float* row = preds + (size_t)p * PRED_COLS;
        float xc = row[0], yc = row[1], w = row[2], h = row[3];
        px1 = xc - w * 0.5f; py1 = yc - h * 0.5f;
        px2 = xc + w * 0.5f; py2 = yc + h * 0.5f;
        areap = fmaxf(px2 - px1, 0.f) * fmaxf(py2 - py1, 0.f);
        pcx = (px1 + px2) * 0.5f; pcy = (py1 + py2) * 0.5f;
        atp = atanf(fmaxf(px2 - px1, EPS_C) / fmaxf(py2 - py1, EPS_C));
    }

    const float VC = (float)(4.0 / (M_PI * M_PI));
    float* out = cost + (size_t)g0 * NP + p;

#pragma unroll 5
    for (int i = 0; i < GSLAB; ++i) {
        float4 b = sbox[i];
        float4 m = smisc[i];
        float gx1 = b.x, gy1 = b.y, gx2 = b.z, gy2 = b.w;
        float xx1 = fmaxf(px1, gx1), yy1 = fmaxf(py1, gy1);
        float xx2 = fminf(px2, gx2), yy2 = fminf(py2, gy2);
        float inter = fmaxf(xx2 - xx1, 0.f) * fmaxf(yy2 - yy1, 0.f);
        float uni = areap + m.x - inter + EPS_C;
        float iou = inter * fast_rcp(uni);
        float dx = pcx - m.y, dy = pcy - m.z;
        float cd2 = dx * dx + dy * dy;
        float cw = fmaxf(fmaxf(px2, gx2) - fminf(px1, gx1), EPS_C);
        float ch = fmaxf(fmaxf(py2, gy2) - fminf(py1, gy1), EPS_C);
        float c2 = cw * cw + ch * ch + EPS_C;
        float dat = m.w - atp;
        float v = VC * dat * dat;
        float alpha_t = v * fast_rcp(1.f - iou + v + EPS_C);
        float ciou = iou - cd2 * fast_rcp(c2) - alpha_t * v;

        float prob = probs[(size_t)scls[i] + p];
        float cst = ALPHA_C * (1.f - prob) +
                    BETA_C * (1.f - fminf(fmaxf(ciou, 0.f), 1.f));
        out[(size_t)i * NP] = cst;
    }
}

// lexicographic (val, idx) wave-min butterfly; all 64 lanes converge.
__device__ __forceinline__ void wave_lexmin(float& v, int& i) {
#pragma unroll
    for (int off = 32; off >= 1; off >>= 1) {
        float ov = __shfl_xor(v, off);
        int   oi = __shfl_xor(i, off);
        if (ov < v || (ov == v && oi < i)) { v = ov; i = oi; }
    }
}

// ---------------------------------------------------------------------------
// Kernel B: partial top-10 per (gt, chunk) -- two-phase wave-cooperative.
// Phase 1: lane-local min (pipelined fmin chain, BW-bound) then 10 rounds of
// wave-lexmin knockout over the 64 lane-mins -> thr_seed (= 10th-smallest
// lane-min).  Conservative: the 10 smallest lane-mins are 10 distinct real
// elements <= thr_seed, so any x > thr_seed has >=10 lexicographic
// predecessors -> safe reject.  Phase 2: R5-validated ballot+shfl exact
// insertion, thr starts at the seed (kills the cold-start serialization
// flood that kept R6 at 77us) and tightens to min(seed, list-10th).
// ---------------------------------------------------------------------------
__global__ __launch_bounds__(TPB) void topk_partial(
    const float* __restrict__ cost, float* __restrict__ lc, int* __restrict__ li)
{
    int g  = blockIdx.x / BCH;
    int ch = blockIdx.x % BCH;
    const float4* b4 = (const float4*)(cost + (size_t)g * NP + (size_t)ch * CHUNK);
    const int NV = CHUNK / 4;  // 2500

    const int lane = threadIdx.x & 63;
    const int wid  = threadIdx.x >> 6;

    // ---- phase 1: lane-local min, then wave 10th-smallest as thr seed
    float lmin = INFINITY;
    for (int i = threadIdx.x; i < NV; i += TPB) {
        float4 v = b4[i];
        lmin = fminf(lmin, fminf(fminf(v.x, v.y), fminf(v.z, v.w)));
    }
    float thr;
    {
        float v = lmin;
        float last = INFINITY;
#pragma unroll
        for (int k = 0; k < KCAP; ++k) {
            float wv = v; int wi = lane;
            wave_lexmin(wv, wi);
            last = wv;
            if (lane == wi) v = INFINITY;   // knock out this round's winner
        }
        thr = last;
    }

    // ---- phase 2: exact top-10 (chunk is L2/L3-hot from phase 1)
    float ev = INFINITY;       // this lane's list entry (valid for lane < 10)
    int   ei = 0x7fffffff;

    for (int i = threadIdx.x; i < NV; i += TPB) {
        float4 v = b4[i];
        int ib = ch * CHUNK + i * 4;
        float vmin = fminf(fminf(v.x, v.y), fminf(v.z, v.w));
        if (__ballot(vmin <= thr) == 0ull) continue;

        float vq[4] = {v.x, v.y, v.z, v.w};
#pragma unroll
        for (int q = 0; q < 4; ++q) {
            unsigned long long m = __ballot(vq[q] <= thr);
            while (m) {
                int l = __ffsll(m) - 1;
                m &= m - 1;
                float cv = __shfl(vq[q], l);
                int   ci = __shfl(ib, l) + q;
                if (!(cv <= thr)) continue;   // thr may have tightened
                bool prec = (ev < cv) || (ev == cv && ei < ci);
                unsigned long long bb = __ballot(prec) & 0x3FFull;
                int pos = __popcll(bb);
                if (pos < KCAP) {
                    float pev = __shfl_up(ev, 1);
                    int   pei = __shfl_up(ei, 1);
                    if (lane > pos && lane < KCAP) { ev = pev; ei = pei; }
                    if (lane == pos)               { ev = cv;  ei = ci;  }
                    thr = fminf(thr, __shfl(ev, KCAP - 1));
                }
            }
        }
    }

    __shared__ float swv[4 * KCAP];
    __shared__ int   swi[4 * KCAP];
    if (lane < KCAP) { swv[wid * KCAP + lane] = ev; swi[wid * KCAP + lane] = ei; }
    __syncthreads();

    if (wid == 0) {
        float mv = (lane < 4 * KCAP) ? swv[lane] : INFINITY;
        int   mi = (lane < 4 * KCAP) ? swi[lane] : 0x7fffffff;
        float* oc = lc + ((size_t)g * BCH + ch) * KCAP;
        int*   oi = li + ((size_t)g * BCH + ch) * KCAP;
        for (int k = 0; k < KCAP; ++k) {
            float wv = mv; int wi = mi;
            wave_lexmin(wv, wi);
            if (lane == 0) { oc[k] = wv; oi[k] = wi; }
            if (mv == wv && mi == wi) { mv = INFINITY; mi = 0x7fffffff; }
        }
    }
}

// ---------------------------------------------------------------------------
// Kernel C: merge the BCH partial lists per gt (100 entries, 2 per lane),
// wave-parallel selection; Kt from epoch schedule (banker's rounding).
// ---------------------------------------------------------------------------
__global__ __launch_bounds__(64) void topk_final(
    const float* __restrict__ lc, const int* __restrict__ li,
    const int* __restrict__ epoch, const int* __restrict__ total_epochs,
    float* __restrict__ out_assign)
{
    const int NE = BCH * KCAP;  // 100
    int g = blockIdx.x;
    int lane = threadIdx.x;

    float e0 = INFINITY, e1 = INFINITY;
    int   i0 = 0x7fffffff, i1 = 0x7fffffff;
    {
        const float* pc = lc + (size_t)g * NE;
        const int*   pi = li + (size_t)g * NE;
        e0 = pc[lane]; i0 = pi[lane];                      // lanes 0..63
        if (lane < NE - 64) { e1 = pc[lane + 64]; i1 = pi[lane + 64]; }
    }

    int ep = epoch[0], te = total_epochs[0];
    int denom = te - 1; if (denom < 1) denom = 1;
    double tt = (double)ep / (double)denom;
    int K = (int)rint(10.0 - 9.0 * tt);
    if (K < 1) K = 1; if (K > 10) K = 10;
    int Kt = (K < NP) ? K : NP;

    for (int k = 0; k < Kt; ++k) {
        bool sel0 = (e0 < e1) || (e0 == e1 && i0 < i1);
        float wv = sel0 ? e0 : e1;
        int   wi = sel0 ? i0 : i1;
        wave_lexmin(wv, wi);
        if (lane == 0) {
            out_assign[2 * ((size_t)g * Kt + k) + 0] = (float)wi;
            out_assign[2 * ((size_t)g * Kt + k) + 1] = (float)g;
        }
        if (e0 == wv && i0 == wi) { e0 = INFINITY; i0 = 0x7fffffff; }
        if (e1 == wv && i1 == wi) { e1 = INFINITY; i1 = 0x7fffffff; }
    }
}

// ---------------------------------------------------------------------------
extern "C" void kernel_launch(void* const* d_in, const int* in_sizes, int n_in,
                              void* d_out, int out_size, void* d_ws, size_t ws_size,
                              hipStream_t stream)
{
    const float* preds        = (const float*)d_in[0];
    const float* gt_boxes     = (const float*)d_in[1];
    const int*   gt_classes   = (const int*)d_in[2];
    const int*   epoch        = (const int*)d_in[3];
    const int*   total_epochs = (const int*)d_in[4];

    float* cost       = (float*)d_out;
    float* out_assign = cost + (size_t)NG * NP;

    const int ablocks = (NP + TPB - 1) / TPB;  // 391
    size_t probBytes  = (size_t)NC * NP * sizeof(float);   // 32 MB, [c][p]
    size_t packBytes  = (size_t)NP * 8 * sizeof(float);    // 3.2 MB
    size_t listBytes  = (size_t)NG * BCH * KCAP * 8;       // 240 KB

    char* wsp = (char*)d_ws;
    bool usePack = ws_size >= probBytes + packBytes + listBytes;

    float*  probs = (float*)wsp;
    float4* bA    = (float4*)(wsp + probBytes);
    float4* bB    = (float4*)(wsp + probBytes + packBytes / 2);
    float*  lc; int* li;
    if (usePack) {
        lc = (float*)(wsp + probBytes + packBytes);
        li = (int*)  (wsp + probBytes + packBytes + listBytes / 2);
    } else {
        lc = (float*)(wsp + probBytes);
        li = (int*)  (wsp + probBytes + listBytes / 2);
    }

    if (usePack) {
        prep_kernel<<<dim3(ablocks, NCT + 1), TPB, 0, stream>>>(preds, probs, bA, bB);
        cost_kernel<true ><<<dim3(ablocks, NSLAB), TPB, 0, stream>>>(
            preds, gt_boxes, gt_classes, cost, probs, bA, bB);
    } else {
        prep_kernel<<<dim3(ablocks, NCT), TPB, 0, stream>>>(preds, probs, bA, bB);
        cost_kernel<false><<<dim3(ablocks, NSLAB), TPB, 0, stream>>>(
            preds, gt_boxes, gt_classes, cost, probs, bA, bB);
    }

    topk_partial<<<NG * BCH, TPB, 0, stream>>>(cost, lc, li);
    topk_final<<<NG, 64, 0, stream>>>(lc, li, epoch, total_epochs, out_assign);
}

// Round 8
// 245.473 us; speedup vs baseline: 1.5498x; 1.0235x over previous
//
#include <hip/hip_runtime.h>
#include <math.h>

#define NG 300
#define NP 100000
#define NC 80
#define PRED_COLS 85   // 5 + NC
#define ALPHA_C 0.75f
#define BETA_C  1.0f
#define EPS_C   1e-7f
#define TPB 256
#define NBLK ((NP + TPB - 1) / TPB)   // 391 pred blocks
#define BCH 10                // top-k chunks per gt row
#define CHUNK (NP / BCH)      // 10000
#define KCAP 10
#define NSLAB 20              // gt slabs for cost kernel
#define GSLAB (NG / NSLAB)    // 15

__device__ __forceinline__ float fast_rcp(float x) {
    return __builtin_amdgcn_rcpf(x);
}

__device__ __forceinline__ float wave_min(float v) {
#pragma unroll
    for (int off = 32; off >= 1; off >>= 1)
        v = fminf(v, __shfl_xor(v, off));
    return v;
}

// lexicographic (val, idx) wave-min butterfly; all 64 lanes converge.
__device__ __forceinline__ void wave_lexmin(float& v, int& i) {
#pragma unroll
    for (int off = 32; off >= 1; off >>= 1) {
        float ov = __shfl_xor(v, off);
        int   oi = __shfl_xor(i, off);
        if (ov < v || (ov == v && oi < i)) { v = ov; i = oi; }
    }
}

// ---------------------------------------------------------------------------
// Kernel P: prep, 2 half-row passes (replaces the 5-tile version whose 64B-of-
// 128B-line reads over-fetched ~2.5x).  y==0: pack box-derived float4s +
// classes 0..39; y==1: classes 40..79.  Row walk is L1-amortized across the
// wave; prob writes are class-major coalesced.
// ---------------------------------------------------------------------------
__global__ __launch_bounds__(TPB) void prep_kernel(
    const float* __restrict__ preds, float* __restrict__ probs,
    float4* __restrict__ bA, float4* __restrict__ bB)
{
    int p = blockIdx.x * TPB + threadIdx.x;
    if (p >= NP) return;
    const float* row = preds + (size_t)p * PRED_COLS;
    if (blockIdx.y == 0) {
        float xc = row[0], yc = row[1], w = row[2], h = row[3];
        float px1 = xc - w * 0.5f, py1 = yc - h * 0.5f;
        float px2 = xc + w * 0.5f, py2 = yc + h * 0.5f;
        float4 a = {px1, py1, px2, py2};
        float4 b;
        b.x = fmaxf(px2 - px1, 0.f) * fmaxf(py2 - py1, 0.f);
        b.y = (px1 + px2) * 0.5f;
        b.z = (py1 + py2) * 0.5f;
        b.w = atanf(fmaxf(px2 - px1, EPS_C) / fmaxf(py2 - py1, EPS_C));
        bA[p] = a; bB[p] = b;
#pragma unroll
        for (int c = 0; c < 40; ++c)
            probs[(size_t)c * NP + p] = fast_rcp(1.f + expf(-row[5 + c]));
    } else {
#pragma unroll
        for (int c = 40; c < 80; ++c)
            probs[(size_t)c * NP + p] = fast_rcp(1.f + expf(-row[5 + c]));
    }
}

// ---------------------------------------------------------------------------
// Kernel A: cost matrix.  grid = (391, NSLAB); block = 256 preds x 15 gts.
// Fully-unrolled gt loop; the 15 per-gt probs preloaded to registers (inner
// loop has ZERO global loads).  Byproduct: per-(gt, block) min of cst via
// fmin butterfly + LDS combine -> mins[g][block] (threshold seed for topk,
// eliminating topk's threshold-discovery pass over the 120MB matrix).
// No early return: invalid lanes (p>=NP) use clamped loads, contribute INF.
// ---------------------------------------------------------------------------
template <bool USE_PACK>
__global__ __launch_bounds__(TPB) void cost_kernel(
    const float* __restrict__ preds, const float* __restrict__ gt_boxes,
    const int* __restrict__ gt_classes, float* __restrict__ cost,
    const float* __restrict__ probs,
    const float4* __restrict__ bA, const float4* __restrict__ bB,
    float* __restrict__ mins)
{
    __shared__ float4 sbox[GSLAB];   // gx1, gy1, gx2, gy2
    __shared__ float4 smisc[GSLAB];  // area_g, gcx, gcy, atan_g
    __shared__ int    scls[GSLAB];   // class*NP (pack path) or class
    __shared__ float  swmin[4][GSLAB];

    const int g0 = blockIdx.y * GSLAB;
    const int lane = threadIdx.x & 63;
    const int wid  = threadIdx.x >> 6;

    for (int i = threadIdx.x; i < GSLAB; i += TPB) {
        int g = g0 + i;
        float4 b = ((const float4*)gt_boxes)[g];
        float x1 = b.x, y1 = b.y, x2 = b.z, y2 = b.w;
        sbox[i] = b;
        float4 m;
        m.x = fmaxf(x2 - x1, 0.f) * fmaxf(y2 - y1, 0.f);
        m.y = (x1 + x2) * 0.5f;
        m.z = (y1 + y2) * 0.5f;
        m.w = atanf(fmaxf(x2 - x1, EPS_C) / fmaxf(y2 - y1, EPS_C));
        smisc[i] = m;
        scls[i] = USE_PACK ? gt_classes[g] * NP : gt_classes[g];
    }
    __syncthreads();

    const int p = blockIdx.x * TPB + threadIdx.x;
    const bool valid = p < NP;
    const int pc = valid ? p : NP - 1;   // clamp: loads safe, results masked

    float px1, py1, px2, py2, areap, pcx, pcy, atp;
    const float* row = preds + (size_t)pc * PRED_COLS;
    if (USE_PACK) {
        float4 a = bA[pc], b = bB[pc];
        px1 = a.x; py1 = a.y; px2 = a.z; py2 = a.w;
        areap = b.x; pcx = b.y; pcy = b.z; atp = b.w;
    } else {
        float xc = row[0], yc = row[1], w = row[2], h = row[3];
        px1 = xc - w * 0.5f; py1 = yc - h * 0.5f;
        px2 = xc + w * 0.5f; py2 = yc + h * 0.5f;
        areap = fmaxf(px2 - px1, 0.f) * fmaxf(py2 - py1, 0.f);
        pcx = (px1 + px2) * 0.5f; pcy = (py1 + py2) * 0.5f;
        atp = atanf(fmaxf(px2 - px1, EPS_C) / fmaxf(py2 - py1, EPS_C));
    }

    float prob[GSLAB];
#pragma unroll
    for (int i = 0; i < GSLAB; ++i) {
        if (USE_PACK) prob[i] = probs[(size_t)scls[i] + pc];
        else          prob[i] = fast_rcp(1.f + expf(-row[5 + scls[i]]));
    }

    const float VC = (float)(4.0 / (M_PI * M_PI));
    float* out = cost + (size_t)g0 * NP + p;
    float mn[GSLAB];

#pragma unroll
    for (int i = 0; i < GSLAB; ++i) {
        float4 b = sbox[i];
        float4 m = smisc[i];
        float gx1 = b.x, gy1 = b.y, gx2 = b.z, gy2 = b.w;
        float xx1 = fmaxf(px1, gx1), yy1 = fmaxf(py1, gy1);
        float xx2 = fminf(px2, gx2), yy2 = fminf(py2, gy2);
        float inter = fmaxf(xx2 - xx1, 0.f) * fmaxf(yy2 - yy1, 0.f);
        float uni = areap + m.x - inter + EPS_C;
        float iou = inter * fast_rcp(uni);
        float dx = pcx - m.y, dy = pcy - m.z;
        float cd2 = dx * dx + dy * dy;
        float cw = fmaxf(fmaxf(px2, gx2) - fminf(px1, gx1), EPS_C);
        float ch = fmaxf(fmaxf(py2, gy2) - fminf(py1, gy1), EPS_C);
        float c2 = cw * cw + ch * ch + EPS_C;
        float dat = m.w - atp;
        float v = VC * dat * dat;
        float alpha_t = v * fast_rcp(1.f - iou + v + EPS_C);
        float ciou = iou - cd2 * fast_rcp(c2) - alpha_t * v;

        float cst = ALPHA_C * (1.f - prob[i]) +
                    BETA_C * (1.f - fminf(fmaxf(ciou, 0.f), 1.f));
        mn[i] = valid ? cst : INFINITY;
        if (valid) out[(size_t)i * NP] = cst;
    }

    // per-gt block-min: wave butterfly + cross-wave LDS combine
#pragma unroll
    for (int i = 0; i < GSLAB; ++i) {
        float v = wave_min(mn[i]);
        if (lane == 0) swmin[wid][i] = v;
    }
    __syncthreads();
    if (threadIdx.x < GSLAB) {
        int t = threadIdx.x;
        float v = fminf(fminf(swmin[0][t], swmin[1][t]),
                        fminf(swmin[2][t], swmin[3][t]));
        mins[(size_t)(g0 + t) * NBLK + blockIdx.x] = v;
    }
}

// ---------------------------------------------------------------------------
// Kernel T: thr[g] = 10th-smallest of the 391 block-mins of row g.
// Each block-min is a real element of row g and the 10 smallest come from 10
// distinct blocks => 10 distinct elements <= thr => any x > thr has >=10
// strict lexicographic predecessors -> safe reject in topk.
// ---------------------------------------------------------------------------
__global__ __launch_bounds__(64) void thr_kernel(
    const float* __restrict__ mins, float* __restrict__ thr)
{
    int g = blockIdx.x, lane = threadIdx.x;
    const float* m = mins + (size_t)g * NBLK;
    float v[7];
#pragma unroll
    for (int j = 0; j < 7; ++j) {
        int idx = lane + j * 64;
        v[j] = (idx < NBLK) ? m[idx] : INFINITY;
    }
    float last = INFINITY;
    for (int k = 0; k < KCAP; ++k) {
        float lm = v[0];
#pragma unroll
        for (int j = 1; j < 7; ++j) lm = fminf(lm, v[j]);
        float wv = lm; int wi = lane;
        wave_lexmin(wv, wi);           // unique winner lane
        last = wv;
        if (lane == wi) {              // knock out exactly one copy
            bool done = false;
#pragma unroll
            for (int j = 0; j < 7; ++j)
                if (!done && v[j] == lm) { v[j] = INFINITY; done = true; }
        }
    }
    if (lane == 0) thr[g] = last;
}

// ---------------------------------------------------------------------------
// Kernel B: partial top-10 per (gt, chunk) -- SINGLE pass, thr known at entry
// (R7's phase-1 threshold-discovery read of the whole matrix is gone).
// Exact ballot+shfl insertion machinery validated since R5; thr tightens to
// min(seed, running 10th).
// ---------------------------------------------------------------------------
__global__ __launch_bounds__(TPB) void topk_partial(
    const float* __restrict__ cost, const float* __restrict__ thrbuf,
    float* __restrict__ lc, int* __restrict__ li)
{
    int g  = blockIdx.x / BCH;
    int ch = blockIdx.x % BCH;
    const float4* b4 = (const float4*)(cost + (size_t)g * NP + (size_t)ch * CHUNK);
    const int NV = CHUNK / 4;  // 2500

    const int lane = threadIdx.x & 63;
    const int wid  = threadIdx.x >> 6;

    float thr = thrbuf[g];
    float ev = INFINITY;       // this lane's list entry (valid for lane < 10)
    int   ei = 0x7fffffff;

    for (int i = threadIdx.x; i < NV; i += TPB) {
        float4 v = b4[i];
        int ib = ch * CHUNK + i * 4;
        float vmin = fminf(fminf(v.x, v.y), fminf(v.z, v.w));
        if (__ballot(vmin <= thr) == 0ull) continue;

        float vq[4] = {v.x, v.y, v.z, v.w};
#pragma unroll
        for (int q = 0; q < 4; ++q) {
            unsigned long long m = __ballot(vq[q] <= thr);
            while (m) {
                int l = __ffsll(m) - 1;
                m &= m - 1;
                float cv = __shfl(vq[q], l);
                int   ci = __shfl(ib, l) + q;
                if (!(cv <= thr)) continue;   // thr may have tightened
                bool prec = (ev < cv) || (ev == cv && ei < ci);
                unsigned long long bb = __ballot(prec) & 0x3FFull;
                int pos = __popcll(bb);
                if (pos < KCAP) {
                    float pev = __shfl_up(ev, 1);
                    int   pei = __shfl_up(ei, 1);
                    if (lane > pos && lane < KCAP) { ev = pev; ei = pei; }
                    if (lane == pos)               { ev = cv;  ei = ci;  }
                    thr = fminf(thr, __shfl(ev, KCAP - 1));
                }
            }
        }
    }

    __shared__ float swv[4 * KCAP];
    __shared__ int   swi[4 * KCAP];
    if (lane < KCAP) { swv[wid * KCAP + lane] = ev; swi[wid * KCAP + lane] = ei; }
    __syncthreads();

    if (wid == 0) {
        float mv = (lane < 4 * KCAP) ? swv[lane] : INFINITY;
        int   mi = (lane < 4 * KCAP) ? swi[lane] : 0x7fffffff;
        float* oc = lc + ((size_t)g * BCH + ch) * KCAP;
        int*   oi = li + ((size_t)g * BCH + ch) * KCAP;
        for (int k = 0; k < KCAP; ++k) {
            float wv = mv; int wi = mi;
            wave_lexmin(wv, wi);
            if (lane == 0) { oc[k] = wv; oi[k] = wi; }
            if (mv == wv && mi == wi) { mv = INFINITY; mi = 0x7fffffff; }
        }
    }
}

// ---------------------------------------------------------------------------
// Kernel C: merge the BCH partial lists per gt (100 entries, 2 per lane),
// wave-parallel selection; Kt from epoch schedule (banker's rounding).
// ---------------------------------------------------------------------------
__global__ __launch_bounds__(64) void topk_final(
    const float* __restrict__ lc, const int* __restrict__ li,
    const int* __restrict__ epoch, const int* __restrict__ total_epochs,
    float* __restrict__ out_assign)
{
    const int NE = BCH * KCAP;  // 100
    int g = blockIdx.x;
    int lane = threadIdx.x;

    float e0 = INFINITY, e1 = INFINITY;
    int   i0 = 0x7fffffff, i1 = 0x7fffffff;
    {
        const float* pc = lc + (size_t)g * NE;
        const int*   pi = li + (size_t)g * NE;
        e0 = pc[lane]; i0 = pi[lane];
        if (lane < NE - 64) { e1 = pc[lane + 64]; i1 = pi[lane + 64]; }
    }

    int ep = epoch[0], te = total_epochs[0];
    int denom = te - 1; if (denom < 1) denom = 1;
    double tt = (double)ep / (double)denom;
    int K = (int)rint(10.0 - 9.0 * tt);
    if (K < 1) K = 1; if (K > 10) K = 10;
    int Kt = (K < NP) ? K : NP;

    for (int k = 0; k < Kt; ++k) {
        bool sel0 = (e0 < e1) || (e0 == e1 && i0 < i1);
        float wv = sel0 ? e0 : e1;
        int   wi = sel0 ? i0 : i1;
        wave_lexmin(wv, wi);
        if (lane == 0) {
            out_assign[2 * ((size_t)g * Kt + k) + 0] = (float)wi;
            out_assign[2 * ((size_t)g * Kt + k) + 1] = (float)g;
        }
        if (e0 == wv && i0 == wi) { e0 = INFINITY; i0 = 0x7fffffff; }
        if (e1 == wv && i1 == wi) { e1 = INFINITY; i1 = 0x7fffffff; }
    }
}

// ---------------------------------------------------------------------------
extern "C" void kernel_launch(void* const* d_in, const int* in_sizes, int n_in,
                              void* d_out, int out_size, void* d_ws, size_t ws_size,
                              hipStream_t stream)
{
    const float* preds        = (const float*)d_in[0];
    const float* gt_boxes     = (const float*)d_in[1];
    const int*   gt_classes   = (const int*)d_in[2];
    const int*   epoch        = (const int*)d_in[3];
    const int*   total_epochs = (const int*)d_in[4];

    float* cost       = (float*)d_out;
    float* out_assign = cost + (size_t)NG * NP;

    size_t probBytes = (size_t)NC * NP * sizeof(float);   // 32 MB
    size_t packBytes = (size_t)NP * 8 * sizeof(float);    // 3.2 MB
    size_t minsBytes = (size_t)NG * NBLK * sizeof(float); // ~459 KB
    size_t thrBytes  = 1216;                              // 300 floats, padded
    size_t listBytes = (size_t)NG * BCH * KCAP * 8;       // 240 KB

    char* wsp = (char*)d_ws;
    bool usePack = ws_size >= probBytes + packBytes + minsBytes + thrBytes + listBytes;

    float *probs, *minsb, *thrb, *lcb; float4 *bA, *bB; int *lib;
    if (usePack) {
        probs = (float*)wsp;
        bA    = (float4*)(wsp + probBytes);
        bB    = (float4*)(wsp + probBytes + packBytes / 2);
        minsb = (float*)(wsp + probBytes + packBytes);
        thrb  = (float*)(wsp + probBytes + packBytes + minsBytes);
        lcb   = (float*)(wsp + probBytes + packBytes + minsBytes + thrBytes);
        lib   = (int*)  (wsp + probBytes + packBytes + minsBytes + thrBytes + listBytes / 2);
    } else {
        probs = nullptr; bA = nullptr; bB = nullptr;
        minsb = (float*)wsp;
        thrb  = (float*)(wsp + minsBytes);
        lcb   = (float*)(wsp + minsBytes + thrBytes);
        lib   = (int*)  (wsp + minsBytes + thrBytes + listBytes / 2);
    }

    if (usePack) {
        prep_kernel<<<dim3(NBLK, 2), TPB, 0, stream>>>(preds, probs, bA, bB);
        cost_kernel<true ><<<dim3(NBLK, NSLAB), TPB, 0, stream>>>(
            preds, gt_boxes, gt_classes, cost, probs, bA, bB, minsb);
    } else {
        cost_kernel<false><<<dim3(NBLK, NSLAB), TPB, 0, stream>>>(
            preds, gt_boxes, gt_classes, cost, probs, bA, bB, minsb);
    }
    thr_kernel<<<NG, 64, 0, stream>>>(minsb, thrb);
    topk_partial<<<NG * BCH, TPB, 0, stream>>>(cost, thrb, lcb, lib);
    topk_final<<<NG, 64, 0, stream>>>(lcb, lib, epoch, total_epochs, out_assign);
}

// Round 9
// 221.278 us; speedup vs baseline: 1.7193x; 1.1093x over previous
//
#include <hip/hip_runtime.h>
#include <math.h>

#define NG 300
#define NP 100000
#define NC 80
#define PRED_COLS 85   // 5 + NC
#define ALPHA_C 0.75f
#define BETA_C  1.0f
#define EPS_C   1e-7f
#define TPB 256
#define NBLK ((NP + TPB - 1) / TPB)   // 391 pred blocks
#define KCAP 10
#define NSLAB 20              // gt slabs for cost kernel
#define GSLAB (NG / NSLAB)    // 15

__device__ __forceinline__ float fast_rcp(float x) {
    return __builtin_amdgcn_rcpf(x);
}

__device__ __forceinline__ float wave_min(float v) {
#pragma unroll
    for (int off = 32; off >= 1; off >>= 1)
        v = fminf(v, __shfl_xor(v, off));
    return v;
}

// lexicographic (val, idx) wave-min butterfly; all 64 lanes converge.
__device__ __forceinline__ void wave_lexmin(float& v, int& i) {
#pragma unroll
    for (int off = 32; off >= 1; off >>= 1) {
        float ov = __shfl_xor(v, off);
        int   oi = __shfl_xor(i, off);
        if (ov < v || (ov == v && oi < i)) { v = ov; i = oi; }
    }
}

// ---------------------------------------------------------------------------
// Kernel P: prep, 2 half-row passes.  y==0: pack box-derived float4s +
// classes 0..39; y==1: classes 40..79.  Prob writes class-major coalesced.
// ---------------------------------------------------------------------------
__global__ __launch_bounds__(TPB) void prep_kernel(
    const float* __restrict__ preds, float* __restrict__ probs,
    float4* __restrict__ bA, float4* __restrict__ bB)
{
    int p = blockIdx.x * TPB + threadIdx.x;
    if (p >= NP) return;
    const float* row = preds + (size_t)p * PRED_COLS;
    if (blockIdx.y == 0) {
        float xc = row[0], yc = row[1], w = row[2], h = row[3];
        float px1 = xc - w * 0.5f, py1 = yc - h * 0.5f;
        float px2 = xc + w * 0.5f, py2 = yc + h * 0.5f;
        float4 a = {px1, py1, px2, py2};
        float4 b;
        b.x = fmaxf(px2 - px1, 0.f) * fmaxf(py2 - py1, 0.f);
        b.y = (px1 + px2) * 0.5f;
        b.z = (py1 + py2) * 0.5f;
        b.w = atanf(fmaxf(px2 - px1, EPS_C) / fmaxf(py2 - py1, EPS_C));
        bA[p] = a; bB[p] = b;
#pragma unroll
        for (int c = 0; c < 40; ++c)
            probs[(size_t)c * NP + p] = fast_rcp(1.f + expf(-row[5 + c]));
    } else {
#pragma unroll
        for (int c = 40; c < 80; ++c)
            probs[(size_t)c * NP + p] = fast_rcp(1.f + expf(-row[5 + c]));
    }
}

// ---------------------------------------------------------------------------
// Kernel A: cost matrix.  grid = (391, NSLAB); block = 256 preds x 15 gts.
// Inner loop has zero global loads (probs preloaded to registers).
// Byproduct: per-(gt, block) min -> mins[g][block] (enables candidate-block
// pruning in the fused topk: only blocks with min <= thr can hold a top-10).
// ---------------------------------------------------------------------------
template <bool USE_PACK>
__global__ __launch_bounds__(TPB) void cost_kernel(
    const float* __restrict__ preds, const float* __restrict__ gt_boxes,
    const int* __restrict__ gt_classes, float* __restrict__ cost,
    const float* __restrict__ probs,
    const float4* __restrict__ bA, const float4* __restrict__ bB,
    float* __restrict__ mins)
{
    __shared__ float4 sbox[GSLAB];   // gx1, gy1, gx2, gy2
    __shared__ float4 smisc[GSLAB];  // area_g, gcx, gcy, atan_g
    __shared__ int    scls[GSLAB];   // class*NP (pack path) or class
    __shared__ float  swmin[4][GSLAB];

    const int g0 = blockIdx.y * GSLAB;
    const int lane = threadIdx.x & 63;
    const int wid  = threadIdx.x >> 6;

    for (int i = threadIdx.x; i < GSLAB; i += TPB) {
        int g = g0 + i;
        float4 b = ((const float4*)gt_boxes)[g];
        float x1 = b.x, y1 = b.y, x2 = b.z, y2 = b.w;
        sbox[i] = b;
        float4 m;
        m.x = fmaxf(x2 - x1, 0.f) * fmaxf(y2 - y1, 0.f);
        m.y = (x1 + x2) * 0.5f;
        m.z = (y1 + y2) * 0.5f;
        m.w = atanf(fmaxf(x2 - x1, EPS_C) / fmaxf(y2 - y1, EPS_C));
        smisc[i] = m;
        scls[i] = USE_PACK ? gt_classes[g] * NP : gt_classes[g];
    }
    __syncthreads();

    const int p = blockIdx.x * TPB + threadIdx.x;
    const bool valid = p < NP;
    const int pc = valid ? p : NP - 1;   // clamp: loads safe, results masked

    float px1, py1, px2, py2, areap, pcx, pcy, atp;
    const float* row = preds + (size_t)pc * PRED_COLS;
    if (USE_PACK) {
        float4 a = bA[pc], b = bB[pc];
        px1 = a.x; py1 = a.y; px2 = a.z; py2 = a.w;
        areap = b.x; pcx = b.y; pcy = b.z; atp = b.w;
    } else {
        float xc = row[0], yc = row[1], w = row[2], h = row[3];
        px1 = xc - w * 0.5f; py1 = yc - h * 0.5f;
        px2 = xc + w * 0.5f; py2 = yc + h * 0.5f;
        areap = fmaxf(px2 - px1, 0.f) * fmaxf(py2 - py1, 0.f);
        pcx = (px1 + px2) * 0.5f; pcy = (py1 + py2) * 0.5f;
        atp = atanf(fmaxf(px2 - px1, EPS_C) / fmaxf(py2 - py1, EPS_C));
    }

    float prob[GSLAB];
#pragma unroll
    for (int i = 0; i < GSLAB; ++i) {
        if (USE_PACK) prob[i] = probs[(size_t)scls[i] + pc];
        else          prob[i] = fast_rcp(1.f + expf(-row[5 + scls[i]]));
    }

    const float VC = (float)(4.0 / (M_PI * M_PI));
    float* out = cost + (size_t)g0 * NP + p;
    float mn[GSLAB];

#pragma unroll
    for (int i = 0; i < GSLAB; ++i) {
        float4 b = sbox[i];
        float4 m = smisc[i];
        float gx1 = b.x, gy1 = b.y, gx2 = b.z, gy2 = b.w;
        float xx1 = fmaxf(px1, gx1), yy1 = fmaxf(py1, gy1);
        float xx2 = fminf(px2, gx2), yy2 = fminf(py2, gy2);
        float inter = fmaxf(xx2 - xx1, 0.f) * fmaxf(yy2 - yy1, 0.f);
        float uni = areap + m.x - inter + EPS_C;
        float iou = inter * fast_rcp(uni);
        float dx = pcx - m.y, dy = pcy - m.z;
        float cd2 = dx * dx + dy * dy;
        float cw = fmaxf(fmaxf(px2, gx2) - fminf(px1, gx1), EPS_C);
        float ch = fmaxf(fmaxf(py2, gy2) - fminf(py1, gy1), EPS_C);
        float c2 = cw * cw + ch * ch + EPS_C;
        float dat = m.w - atp;
        float v = VC * dat * dat;
        float alpha_t = v * fast_rcp(1.f - iou + v + EPS_C);
        float ciou = iou - cd2 * fast_rcp(c2) - alpha_t * v;

        float cst = ALPHA_C * (1.f - prob[i]) +
                    BETA_C * (1.f - fminf(fmaxf(ciou, 0.f), 1.f));
        mn[i] = valid ? cst : INFINITY;
        if (valid) out[(size_t)i * NP] = cst;
    }

    // per-gt block-min: wave butterfly + cross-wave LDS combine
#pragma unroll
    for (int i = 0; i < GSLAB; ++i) {
        float v = wave_min(mn[i]);
        if (lane == 0) swmin[wid][i] = v;
    }
    __syncthreads();
    if (threadIdx.x < GSLAB) {
        int t = threadIdx.x;
        float v = fminf(fminf(swmin[0][t], swmin[1][t]),
                        fminf(swmin[2][t], swmin[3][t]));
        mins[(size_t)(g0 + t) * NBLK + blockIdx.x] = v;
    }
}

// ---------------------------------------------------------------------------
// Kernel B (fused): per gt -- thr = 10th-smallest block-min (wave-0 knockout);
// gather qualifying blocks (min <= thr; ~10 of 391, ties included, no cap);
// scan ONLY those blocks (~2.5K elements vs 100K) with the exact ballot+shfl
// insertion machinery (R5-validated, order-independent); wave-0 merge of the
// 4 wave lists; Kt from epoch schedule; write assignments.
// Pruning proof: 10 distinct elements (the 10 smallest block-min reps) have
// value <= thr, so any x with value > thr has >=10 strict lex predecessors;
// and x in top-10 => value(x) <= thr => its block min <= thr => gathered.
// ---------------------------------------------------------------------------
__global__ __launch_bounds__(TPB) void topk_fused(
    const float* __restrict__ cost, const float* __restrict__ mins,
    const int* __restrict__ epoch, const int* __restrict__ total_epochs,
    float* __restrict__ out_assign)
{
    const int g = blockIdx.x;
    const int lane = threadIdx.x & 63;
    const int wid  = threadIdx.x >> 6;

    __shared__ float s_thr;
    __shared__ int   s_qn;
    __shared__ int   qlist[NBLK];
    __shared__ float swv[4 * KCAP];
    __shared__ int   swi[4 * KCAP];

    if (threadIdx.x == 0) s_qn = 0;
    __syncthreads();

    const float* mrow = mins + (size_t)g * NBLK;

    // wave 0: thr = 10th-smallest of 391 block-mins (knockout)
    if (wid == 0) {
        float v[7];
#pragma unroll
        for (int j = 0; j < 7; ++j) {
            int idx = lane + j * 64;
            v[j] = (idx < NBLK) ? mrow[idx] : INFINITY;
        }
        float last = INFINITY;
        for (int k = 0; k < KCAP; ++k) {
            float lm = v[0];
#pragma unroll
            for (int j = 1; j < 7; ++j) lm = fminf(lm, v[j]);
            float wv = lm; int wi = lane;
            wave_lexmin(wv, wi);
            last = wv;
            if (lane == wi) {
                bool done = false;
#pragma unroll
                for (int j = 0; j < 7; ++j)
                    if (!done && v[j] == lm) { v[j] = INFINITY; done = true; }
            }
        }
        if (lane == 0) s_thr = last;
    }
    __syncthreads();
    const float thr0 = s_thr;

    // gather qualifying blocks (order-independent downstream, atomics fine)
    for (int b = threadIdx.x; b < NBLK; b += TPB)
        if (mrow[b] <= thr0) qlist[atomicAdd(&s_qn, 1)] = b;
    __syncthreads();
    const int qn = s_qn;

    float thr = thr0;
    float ev = INFINITY; int ei = 0x7fffffff;

    for (int qi = wid; qi < qn; qi += 4) {
        const int b = qlist[qi];
        const int ib = b * TPB + lane * 4;
        float vq[4];
        if (b == NBLK - 1) {
#pragma unroll
            for (int q = 0; q < 4; ++q)
                vq[q] = (ib + q < NP) ? cost[(size_t)g * NP + ib + q] : INFINITY;
        } else {
            float4 v = *(const float4*)(cost + (size_t)g * NP + ib);
            vq[0] = v.x; vq[1] = v.y; vq[2] = v.z; vq[3] = v.w;
        }
#pragma unroll
        for (int q = 0; q < 4; ++q) {
            unsigned long long m = __ballot(vq[q] <= thr);
            while (m) {
                int l = __ffsll(m) - 1;
                m &= m - 1;
                float cv = __shfl(vq[q], l);
                int   ci = __shfl(ib, l) + q;
                if (!(cv <= thr)) continue;   // thr may have tightened
                bool prec = (ev < cv) || (ev == cv && ei < ci);
                unsigned long long bb = __ballot(prec) & 0x3FFull;
                int pos = __popcll(bb);
                if (pos < KCAP) {
                    float pev = __shfl_up(ev, 1);
                    int   pei = __shfl_up(ei, 1);
                    if (lane > pos && lane < KCAP) { ev = pev; ei = pei; }
                    if (lane == pos)               { ev = cv;  ei = ci;  }
                    thr = fminf(thr, __shfl(ev, KCAP - 1));
                }
            }
        }
    }

    if (lane < KCAP) { swv[wid * KCAP + lane] = ev; swi[wid * KCAP + lane] = ei; }
    __syncthreads();

    if (wid == 0) {
        float mv = (lane < 4 * KCAP) ? swv[lane] : INFINITY;
        int   mi = (lane < 4 * KCAP) ? swi[lane] : 0x7fffffff;

        int ep = epoch[0], te = total_epochs[0];
        int denom = te - 1; if (denom < 1) denom = 1;
        double tt = (double)ep / (double)denom;
        int K = (int)rint(10.0 - 9.0 * tt);
        if (K < 1) K = 1; if (K > 10) K = 10;
        int Kt = (K < NP) ? K : NP;

        for (int k = 0; k < Kt; ++k) {
            float wv = mv; int wi = mi;
            wave_lexmin(wv, wi);
            if (lane == 0) {
                out_assign[2 * ((size_t)g * Kt + k) + 0] = (float)wi;
                out_assign[2 * ((size_t)g * Kt + k) + 1] = (float)g;
            }
            if (mv == wv && mi == wi) { mv = INFINITY; mi = 0x7fffffff; }
        }
    }
}

// ---------------------------------------------------------------------------
extern "C" void kernel_launch(void* const* d_in, const int* in_sizes, int n_in,
                              void* d_out, int out_size, void* d_ws, size_t ws_size,
                              hipStream_t stream)
{
    const float* preds        = (const float*)d_in[0];
    const float* gt_boxes     = (const float*)d_in[1];
    const int*   gt_classes   = (const int*)d_in[2];
    const int*   epoch        = (const int*)d_in[3];
    const int*   total_epochs = (const int*)d_in[4];

    float* cost       = (float*)d_out;
    float* out_assign = cost + (size_t)NG * NP;

    size_t probBytes = (size_t)NC * NP * sizeof(float);   // 32 MB
    size_t packBytes = (size_t)NP * 8 * sizeof(float);    // 3.2 MB
    size_t minsBytes = (size_t)NG * NBLK * sizeof(float); // ~459 KB

    char* wsp = (char*)d_ws;
    bool usePack = ws_size >= probBytes + packBytes + minsBytes;

    float *probs, *minsb; float4 *bA, *bB;
    if (usePack) {
        probs = (float*)wsp;
        bA    = (float4*)(wsp + probBytes);
        bB    = (float4*)(wsp + probBytes + packBytes / 2);
        minsb = (float*)(wsp + probBytes + packBytes);
    } else {
        probs = nullptr; bA = nullptr; bB = nullptr;
        minsb = (float*)wsp;
    }

    if (usePack) {
        prep_kernel<<<dim3(NBLK, 2), TPB, 0, stream>>>(preds, probs, bA, bB);
        cost_kernel<true ><<<dim3(NBLK, NSLAB), TPB, 0, stream>>>(
            preds, gt_boxes, gt_classes, cost, probs, bA, bB, minsb);
    } else {
        cost_kernel<false><<<dim3(NBLK, NSLAB), TPB, 0, stream>>>(
            preds, gt_boxes, gt_classes, cost, probs, bA, bB, minsb);
    }
    topk_fused<<<NG, TPB, 0, stream>>>(cost, minsb, epoch, total_epochs, out_assign);
}

// Round 10
// 214.893 us; speedup vs baseline: 1.7704x; 1.0297x over previous
//
#include <hip/hip_runtime.h>
#include <math.h>

#define NG 300
#define NP 100000
#define NC 80
#define PRED_COLS 85   // 5 + NC
#define ALPHA_C 0.75f
#define BETA_C  1.0f
#define EPS_C   1e-7f
#define TPB 256
#define VEC 4                          // preds per thread in cost kernel
#define BLKP (TPB * VEC)               // 1024 preds per cost block
#define NBLK4 ((NP + BLKP - 1) / BLKP) // 98 pred blocks
#define KCAP 10
#define NSLAB 20              // gt slabs for cost kernel
#define GSLAB (NG / NSLAB)    // 15

__device__ __forceinline__ float fast_rcp(float x) {
    return __builtin_amdgcn_rcpf(x);
}

__device__ __forceinline__ float wave_min(float v) {
#pragma unroll
    for (int off = 32; off >= 1; off >>= 1)
        v = fminf(v, __shfl_xor(v, off));
    return v;
}

// lexicographic (val, idx) wave-min butterfly; all 64 lanes converge.
__device__ __forceinline__ void wave_lexmin(float& v, int& i) {
#pragma unroll
    for (int off = 32; off >= 1; off >>= 1) {
        float ov = __shfl_xor(v, off);
        int   oi = __shfl_xor(i, off);
        if (ov < v || (ov == v && oi < i)) { v = ov; i = oi; }
    }
}

// ---------------------------------------------------------------------------
// Kernel P: prep, 2 half-row passes.  y==0: pack box-derived float4s +
// classes 0..39; y==1: classes 40..79.  Prob writes class-major coalesced.
// ---------------------------------------------------------------------------
__global__ __launch_bounds__(TPB) void prep_kernel(
    const float* __restrict__ preds, float* __restrict__ probs,
    float4* __restrict__ bA, float4* __restrict__ bB)
{
    int p = blockIdx.x * TPB + threadIdx.x;
    if (p >= NP) return;
    const float* row = preds + (size_t)p * PRED_COLS;
    if (blockIdx.y == 0) {
        float xc = row[0], yc = row[1], w = row[2], h = row[3];
        float px1 = xc - w * 0.5f, py1 = yc - h * 0.5f;
        float px2 = xc + w * 0.5f, py2 = yc + h * 0.5f;
        float4 a = {px1, py1, px2, py2};
        float4 b;
        b.x = fmaxf(px2 - px1, 0.f) * fmaxf(py2 - py1, 0.f);
        b.y = (px1 + px2) * 0.5f;
        b.z = (py1 + py2) * 0.5f;
        b.w = atanf(fmaxf(px2 - px1, EPS_C) / fmaxf(py2 - py1, EPS_C));
        bA[p] = a; bB[p] = b;
#pragma unroll
        for (int c = 0; c < 40; ++c)
            probs[(size_t)c * NP + p] = fast_rcp(1.f + expf(-row[5 + c]));
    } else {
#pragma unroll
        for (int c = 40; c < 80; ++c)
            probs[(size_t)c * NP + p] = fast_rcp(1.f + expf(-row[5 + c]));
    }
}

// ---------------------------------------------------------------------------
// Kernel A: cost matrix, 4 preds/thread.  grid = (98, NSLAB); block covers
// 1024 preds x 15 gts.  Per-gt LDS reads, addressing, and loop overhead are
// amortized over 4 pairs; prob read is one coalesced dwordx4 from L2-hot
// probs; store is dwordx4.  Byproduct: per-(gt, block) min -> mins[g][98].
// ---------------------------------------------------------------------------
template <bool USE_PACK>
__global__ __launch_bounds__(TPB) void cost_kernel(
    const float* __restrict__ preds, const float* __restrict__ gt_boxes,
    const int* __restrict__ gt_classes, float* __restrict__ cost,
    const float* __restrict__ probs,
    const float4* __restrict__ bA, const float4* __restrict__ bB,
    float* __restrict__ mins)
{
    __shared__ float4 sbox[GSLAB];   // gx1, gy1, gx2, gy2
    __shared__ float4 smisc[GSLAB];  // area_g, gcx, gcy, atan_g
    __shared__ int    scls[GSLAB];   // class*NP (pack path) or class
    __shared__ float  swmin[4][GSLAB];

    const int g0 = blockIdx.y * GSLAB;
    const int lane = threadIdx.x & 63;
    const int wid  = threadIdx.x >> 6;

    for (int i = threadIdx.x; i < GSLAB; i += TPB) {
        int g = g0 + i;
        float4 b = ((const float4*)gt_boxes)[g];
        float x1 = b.x, y1 = b.y, x2 = b.z, y2 = b.w;
        sbox[i] = b;
        float4 m;
        m.x = fmaxf(x2 - x1, 0.f) * fmaxf(y2 - y1, 0.f);
        m.y = (x1 + x2) * 0.5f;
        m.z = (y1 + y2) * 0.5f;
        m.w = atanf(fmaxf(x2 - x1, EPS_C) / fmaxf(y2 - y1, EPS_C));
        smisc[i] = m;
        scls[i] = USE_PACK ? gt_classes[g] * NP : gt_classes[g];
    }
    __syncthreads();

    const int p0 = blockIdx.x * BLKP + threadIdx.x * VEC;
    const bool full = (p0 + VEC - 1) < NP;   // whole-float4 valid

    float px1[VEC], py1[VEC], px2[VEC], py2[VEC];
    float areap[VEC], pcx[VEC], pcy[VEC], atp[VEC];
    bool vld[VEC];
#pragma unroll
    for (int u = 0; u < VEC; ++u) {
        int p = p0 + u;
        vld[u] = p < NP;
        int pc = vld[u] ? p : NP - 1;
        if (USE_PACK) {
            float4 a = bA[pc], b = bB[pc];
            px1[u] = a.x; py1[u] = a.y; px2[u] = a.z; py2[u] = a.w;
            areap[u] = b.x; pcx[u] = b.y; pcy[u] = b.z; atp[u] = b.w;
        } else {
            const float* row = preds + (size_t)pc * PRED_COLS;
            float xc = row[0], yc = row[1], w = row[2], h = row[3];
            px1[u] = xc - w * 0.5f; py1[u] = yc - h * 0.5f;
            px2[u] = xc + w * 0.5f; py2[u] = yc + h * 0.5f;
            areap[u] = fmaxf(px2[u] - px1[u], 0.f) * fmaxf(py2[u] - py1[u], 0.f);
            pcx[u] = (px1[u] + px2[u]) * 0.5f; pcy[u] = (py1[u] + py2[u]) * 0.5f;
            atp[u] = atanf(fmaxf(px2[u] - px1[u], EPS_C) / fmaxf(py2[u] - py1[u], EPS_C));
        }
    }

    const float VC = (float)(4.0 / (M_PI * M_PI));

#pragma unroll
    for (int i = 0; i < GSLAB; ++i) {
        float4 b = sbox[i];
        float4 m = smisc[i];
        float gx1 = b.x, gy1 = b.y, gx2 = b.z, gy2 = b.w;

        float pr[VEC];
        if (USE_PACK) {
            if (full) {
                float4 pv = *(const float4*)(probs + (size_t)scls[i] + p0);
                pr[0] = pv.x; pr[1] = pv.y; pr[2] = pv.z; pr[3] = pv.w;
            } else {
#pragma unroll
                for (int u = 0; u < VEC; ++u)
                    pr[u] = probs[(size_t)scls[i] + (vld[u] ? p0 + u : NP - 1)];
            }
        } else {
#pragma unroll
            for (int u = 0; u < VEC; ++u) {
                int pc = vld[u] ? p0 + u : NP - 1;
                pr[u] = fast_rcp(1.f + expf(-preds[(size_t)pc * PRED_COLS + 5 + scls[i]]));
            }
        }

        float cst[VEC];
#pragma unroll
        for (int u = 0; u < VEC; ++u) {
            float xx1 = fmaxf(px1[u], gx1), yy1 = fmaxf(py1[u], gy1);
            float xx2 = fminf(px2[u], gx2), yy2 = fminf(py2[u], gy2);
            float inter = fmaxf(xx2 - xx1, 0.f) * fmaxf(yy2 - yy1, 0.f);
            float uni = areap[u] + m.x - inter + EPS_C;
            float iou = inter * fast_rcp(uni);
            float dx = pcx[u] - m.y, dy = pcy[u] - m.z;
            float cd2 = dx * dx + dy * dy;
            float cw = fmaxf(fmaxf(px2[u], gx2) - fminf(px1[u], gx1), EPS_C);
            float ch = fmaxf(fmaxf(py2[u], gy2) - fminf(py1[u], gy1), EPS_C);
            float c2 = cw * cw + ch * ch + EPS_C;
            float dat = m.w - atp[u];
            float v = VC * dat * dat;
            float alpha_t = v * fast_rcp(1.f - iou + v + EPS_C);
            float ciou = iou - cd2 * fast_rcp(c2) - alpha_t * v;
            cst[u] = ALPHA_C * (1.f - pr[u]) +
                     BETA_C * (1.f - fminf(fmaxf(ciou, 0.f), 1.f));
        }

        float* orow = cost + (size_t)(g0 + i) * NP;
        if (full) {
            float4 o = {cst[0], cst[1], cst[2], cst[3]};
            *(float4*)(orow + p0) = o;
        } else {
#pragma unroll
            for (int u = 0; u < VEC; ++u)
                if (vld[u]) orow[p0 + u] = cst[u];
        }

        float mn = INFINITY;
#pragma unroll
        for (int u = 0; u < VEC; ++u)
            mn = fminf(mn, vld[u] ? cst[u] : INFINITY);
        float v = wave_min(mn);
        if (lane == 0) swmin[wid][i] = v;
    }
    __syncthreads();
    if (threadIdx.x < GSLAB) {
        int t = threadIdx.x;
        float v = fminf(fminf(swmin[0][t], swmin[1][t]),
                        fminf(swmin[2][t], swmin[3][t]));
        mins[(size_t)(g0 + t) * NBLK4 + blockIdx.x] = v;
    }
}

// ---------------------------------------------------------------------------
// Kernel B (fused): per gt -- thr = 10th-smallest block-min (wave-0 knockout
// over 98); gather qualifying 1024-wide blocks (min <= thr, ties included);
// scan only those (~10K elements vs 100K) as 4x256 sub-chunks, one per wave,
// with the exact ballot+shfl insertion machinery (order-independent, R5-
// validated); wave-0 merge; Kt from epoch schedule; write assignments.
// Pruning proof: the 10 smallest block-mins are 10 distinct real elements
// <= thr, so any x > thr has >=10 strict lex predecessors; and x in top-10
// => value(x) <= thr => its block min <= thr => block gathered.
// ---------------------------------------------------------------------------
__global__ __launch_bounds__(TPB) void topk_fused(
    const float* __restrict__ cost, const float* __restrict__ mins,
    const int* __restrict__ epoch, const int* __restrict__ total_epochs,
    float* __restrict__ out_assign)
{
    const int g = blockIdx.x;
    const int lane = threadIdx.x & 63;
    const int wid  = threadIdx.x >> 6;

    __shared__ float s_thr;
    __shared__ int   s_qn;
    __shared__ int   qlist[NBLK4];
    __shared__ float swv[4 * KCAP];
    __shared__ int   swi[4 * KCAP];

    if (threadIdx.x == 0) s_qn = 0;
    __syncthreads();

    const float* mrow = mins + (size_t)g * NBLK4;

    // wave 0: thr = 10th-smallest of the 98 block-mins (knockout)
    if (wid == 0) {
        float v[2];
#pragma unroll
        for (int j = 0; j < 2; ++j) {
            int idx = lane + j * 64;
            v[j] = (idx < NBLK4) ? mrow[idx] : INFINITY;
        }
        float last = INFINITY;
        for (int k = 0; k < KCAP; ++k) {
            float lm = fminf(v[0], v[1]);
            float wv = lm; int wi = lane;
            wave_lexmin(wv, wi);
            last = wv;
            if (lane == wi) {
                if (v[0] == lm) v[0] = INFINITY;
                else            v[1] = INFINITY;
            }
        }
        if (lane == 0) s_thr = last;
    }
    __syncthreads();
    const float thr0 = s_thr;

    // gather qualifying blocks (order-independent downstream, atomics fine)
    for (int b = threadIdx.x; b < NBLK4; b += TPB)
        if (mrow[b] <= thr0) qlist[atomicAdd(&s_qn, 1)] = b;
    __syncthreads();
    const int qn = s_qn;

    float thr = thr0;
    float ev = INFINITY; int ei = 0x7fffffff;
    const float* crow = cost + (size_t)g * NP;

    for (int si = wid; si < qn * 4; si += 4) {
        const int b   = qlist[si >> 2];
        const int sub = si & 3;
        const int ib  = b * BLKP + sub * 256 + lane * 4;
        float vq[4];
        if (ib + 3 < NP) {
            float4 v = *(const float4*)(crow + ib);
            vq[0] = v.x; vq[1] = v.y; vq[2] = v.z; vq[3] = v.w;
        } else {
#pragma unroll
            for (int q = 0; q < 4; ++q)
                vq[q] = (ib + q < NP) ? crow[ib + q] : INFINITY;
        }
#pragma unroll
        for (int q = 0; q < 4; ++q) {
            unsigned long long m = __ballot(vq[q] <= thr);
            while (m) {
                int l = __ffsll(m) - 1;
                m &= m - 1;
                float cv = __shfl(vq[q], l);
                int   ci = __shfl(ib, l) + q;
                if (!(cv <= thr)) continue;   // thr may have tightened
                bool prec = (ev < cv) || (ev == cv && ei < ci);
                unsigned long long bb = __ballot(prec) & 0x3FFull;
                int pos = __popcll(bb);
                if (pos < KCAP) {
                    float pev = __shfl_up(ev, 1);
                    int   pei = __shfl_up(ei, 1);
                    if (lane > pos && lane < KCAP) { ev = pev; ei = pei; }
                    if (lane == pos)               { ev = cv;  ei = ci;  }
                    thr = fminf(thr, __shfl(ev, KCAP - 1));
                }
            }
        }
    }

    if (lane < KCAP) { swv[wid * KCAP + lane] = ev; swi[wid * KCAP + lane] = ei; }
    __syncthreads();

    if (wid == 0) {
        float mv = (lane < 4 * KCAP) ? swv[lane] : INFINITY;
        int   mi = (lane < 4 * KCAP) ? swi[lane] : 0x7fffffff;

        int ep = epoch[0], te = total_epochs[0];
        int denom = te - 1; if (denom < 1) denom = 1;
        double tt = (double)ep / (double)denom;
        int K = (int)rint(10.0 - 9.0 * tt);
        if (K < 1) K = 1; if (K > 10) K = 10;
        int Kt = (K < NP) ? K : NP;

        for (int k = 0; k < Kt; ++k) {
            float wv = mv; int wi = mi;
            wave_lexmin(wv, wi);
            if (lane == 0) {
                out_assign[2 * ((size_t)g * Kt + k) + 0] = (float)wi;
                out_assign[2 * ((size_t)g * Kt + k) + 1] = (float)g;
            }
            if (mv == wv && mi == wi) { mv = INFINITY; mi = 0x7fffffff; }
        }
    }
}

// ---------------------------------------------------------------------------
extern "C" void kernel_launch(void* const* d_in, const int* in_sizes, int n_in,
                              void* d_out, int out_size, void* d_ws, size_t ws_size,
                              hipStream_t stream)
{
    const float* preds        = (const float*)d_in[0];
    const float* gt_boxes     = (const float*)d_in[1];
    const int*   gt_classes   = (const int*)d_in[2];
    const int*   epoch        = (const int*)d_in[3];
    const int*   total_epochs = (const int*)d_in[4];

    float* cost       = (float*)d_out;
    float* out_assign = cost + (size_t)NG * NP;

    size_t probBytes = (size_t)NC * NP * sizeof(float);    // 32 MB
    size_t packBytes = (size_t)NP * 8 * sizeof(float);     // 3.2 MB
    size_t minsBytes = (size_t)NG * NBLK4 * sizeof(float); // ~118 KB

    char* wsp = (char*)d_ws;
    bool usePack = ws_size >= probBytes + packBytes + minsBytes;

    float *probs, *minsb; float4 *bA, *bB;
    if (usePack) {
        probs = (float*)wsp;
        bA    = (float4*)(wsp + probBytes);
        bB    = (float4*)(wsp + probBytes + packBytes / 2);
        minsb = (float*)(wsp + probBytes + packBytes);
    } else {
        probs = nullptr; bA = nullptr; bB = nullptr;
        minsb = (float*)wsp;
    }

    const int pblocks = (NP + TPB - 1) / TPB;  // 391 for prep
    if (usePack) {
        prep_kernel<<<dim3(pblocks, 2), TPB, 0, stream>>>(preds, probs, bA, bB);
        cost_kernel<true ><<<dim3(NBLK4, NSLAB), TPB, 0, stream>>>(
            preds, gt_boxes, gt_classes, cost, probs, bA, bB, minsb);
    } else {
        cost_kernel<false><<<dim3(NBLK4, NSLAB), TPB, 0, stream>>>(
            preds, gt_boxes, gt_classes, cost, probs, bA, bB, minsb);
    }
    topk_fused<<<NG, TPB, 0, stream>>>(cost, minsb, epoch, total_epochs, out_assign);
}